// Round 1
// baseline (1333.485 us; speedup 1.0000x reference)
//
#include <hip/hip_runtime.h>
#include <math.h>

#define BB 4
#define CC 512
#define TT 4096
#define NN2 32
#define HH 2048

// ---------------- ChannelwiseLayerNorm over C of [B, C, T] ----------------
// grid: B * (T/64) blocks of 256 threads. Each block: one b, 64 t's.
// 4 channel-groups of 128 channels reduced per thread, combined in LDS.
__global__ __launch_bounds__(256) void ln_kernel(
    const float* __restrict__ x, const float* __restrict__ gamma,
    const float* __restrict__ beta, float* __restrict__ u)
{
  int tile = blockIdx.x & (TT/64 - 1);
  int b    = blockIdx.x >> 6;          // TT/64 == 64
  int tl = threadIdx.x & 63;
  int cg = threadIdx.x >> 6;
  int t = tile*64 + tl;
  const float* xp = x + (size_t)b*CC*TT + t;
  float s = 0.f, s2 = 0.f;
  #pragma unroll 4
  for (int c = cg*128; c < (cg+1)*128; ++c){
    float v = xp[(size_t)c*TT];
    s += v; s2 = fmaf(v, v, s2);
  }
  __shared__ float ls[4][64], ls2[4][64], mean_s[64], inv_s[64];
  ls[cg][tl] = s; ls2[cg][tl] = s2;
  __syncthreads();
  if (threadIdx.x < 64){
    float ss  = ls [0][tl]+ls [1][tl]+ls [2][tl]+ls [3][tl];
    float ss2 = ls2[0][tl]+ls2[1][tl]+ls2[2][tl]+ls2[3][tl];
    float mean = ss * (1.f/CC);
    float var  = ss2 * (1.f/CC) - mean*mean;
    mean_s[tl] = mean;
    inv_s[tl]  = rsqrtf(var + 1e-5f);
  }
  __syncthreads();
  float mean = mean_s[tl], inv = inv_s[tl];
  float* up = u + (size_t)b*CC*TT + t;
  #pragma unroll 4
  for (int c = cg*128; c < (cg+1)*128; ++c){
    float v = xp[(size_t)c*TT];
    up[(size_t)c*TT] = fmaf(gamma[c]*inv, v - mean, beta[c]);
  }
}

// ---------------- S4D: chunked parallel scan + D-skip + exact GELU ----------------
// One wave per (b,c) sequence; 4 sequences per 256-thread block.
// Lane = chunk j (16 chunks of 256 steps) x mode-group g (4 groups of 8 modes).
// Two-pass scan: local carries -> prefix combine with w^256 -> rescan emitting y.
// u staged in LDS with an XOR-on-float4-index swizzle to kill the 16-way
// bank conflict of stride-1KB chunk reads.
__global__ __launch_bounds__(256) void s4d_kernel(
    const float* __restrict__ u, const float* __restrict__ log_dt,
    const float* __restrict__ C_re, const float* __restrict__ C_im,
    const float* __restrict__ log_A_real, const float* __restrict__ A_imag,
    const float* __restrict__ Dp, float* __restrict__ gout)
{
  __shared__ float4 u4[4][TT/4];              // 64 KiB
  __shared__ float carry[4][NN2][16][2];      // 16 KiB
  const int tid = threadIdx.x;
  const int wv   = tid >> 6;                  // sequence slot in block
  const int lane = tid & 63;
  const int j = lane >> 2;                    // chunk 0..15
  const int g = lane & 3;                     // mode group 0..3
  const int seq = blockIdx.x*4 + wv;
  const int b = seq / CC, c = seq % CC;

  // cooperative swizzled load of u[b,c,:] into LDS
  const float4* src4 = (const float4*)(u + (size_t)seq*TT);
  float4* uw4 = &u4[wv][0];
  for (int i = lane; i < TT/4; i += 64)
    uw4[i ^ ((i>>6)&7)] = src4[i];

  // per-thread mode constants (8 modes)
  float wre[8], wim[8], okr[8], oki[8];
  float dt = expf(log_dt[c]);
  #pragma unroll
  for (int m = 0; m < 8; ++m){
    int n = g*8 + m;
    float Ar = -expf(log_A_real[c*NN2 + n]);
    float Ai = A_imag[c*NN2 + n];
    float dAr = Ar*dt, dAi = Ai*dt;
    float er = expf(dAr);
    float sw_, cw_; sincosf(dAi, &sw_, &cw_);
    wre[m] = er*cw_; wim[m] = er*sw_;
    // Cd = (C_re + i C_im) * (E - 1) / A
    float nr = wre[m] - 1.0f, ni = wim[m];
    float inv = 1.0f/(Ar*Ar + Ai*Ai);
    float qr = (nr*Ar + ni*Ai)*inv;
    float qi = (ni*Ar - nr*Ai)*inv;
    float Cr = C_re[c*NN2 + n], Ci = C_im[c*NN2 + n];
    float cdr = Cr*qr - Ci*qi;
    float cdi = Cr*qi + Ci*qr;
    okr[m] =  2.0f*cdr;
    oki[m] = -2.0f*cdi;
  }

  // ---- Phase A: local chunk scan from zero state ----
  float sr[8], si[8];
  #pragma unroll
  for (int m = 0; m < 8; ++m){ sr[m]=0.f; si[m]=0.f; }
  const int base = j*64;       // float4 index of chunk start
  const int sw = j & 7;
  for (int q = 0; q < 64; ++q){
    float4 uq = uw4[(base+q) ^ sw];
    float uvals[4] = {uq.x, uq.y, uq.z, uq.w};
    #pragma unroll
    for (int s = 0; s < 4; ++s){
      float uv = uvals[s];
      #pragma unroll
      for (int m = 0; m < 8; ++m){
        float nsr = fmaf(wre[m], sr[m], fmaf(-wim[m], si[m], uv));
        float nsi = fmaf(wre[m], si[m], wim[m]*sr[m]);
        sr[m] = nsr; si[m] = nsi;
      }
    }
  }
  #pragma unroll
  for (int m = 0; m < 8; ++m){
    carry[wv][g*8+m][j][0] = sr[m];
    carry[wv][g*8+m][j][1] = si[m];
  }
  __syncthreads();

  // ---- prefix combine across chunks: 128 (seq,mode) pairs ----
  if (tid < 4*NN2){
    int sq = tid >> 5, n = tid & 31;
    int cc2 = (blockIdx.x*4 + sq) % CC;
    float dt2 = expf(log_dt[cc2]);
    float Ar = -expf(log_A_real[cc2*NN2 + n]);
    float Ai = A_imag[cc2*NN2 + n];
    float mr = Ar*dt2*256.0f, mi = Ai*dt2*256.0f;
    float er = expf(mr);
    float sw_, cw_; sincosf(mi, &sw_, &cw_);
    float wMr = er*cw_, wMi = er*sw_;
    float Er = 0.f, Ei = 0.f;
    for (int q = 0; q < 16; ++q){
      float cr = carry[sq][n][q][0], ci = carry[sq][n][q][1];
      carry[sq][n][q][0] = Er; carry[sq][n][q][1] = Ei;   // chunk-start state
      float nEr = cr + wMr*Er - wMi*Ei;
      float nEi = ci + wMr*Ei + wMi*Er;
      Er = nEr; Ei = nEi;
    }
  }
  __syncthreads();

  // ---- Phase B: rescan with corrected initial state, emit gelu(conv + u*D) ----
  #pragma unroll
  for (int m = 0; m < 8; ++m){
    sr[m] = carry[wv][g*8+m][j][0];
    si[m] = carry[wv][g*8+m][j][1];
  }
  float Dc = Dp[c];
  for (int q = 0; q < 64; ++q){
    float4 uq = uw4[(base+q) ^ sw];
    float uvals[4] = {uq.x, uq.y, uq.z, uq.w};
    float res[4];
    #pragma unroll
    for (int s = 0; s < 4; ++s){
      float uv = uvals[s];
      float part = 0.f;
      #pragma unroll
      for (int m = 0; m < 8; ++m){
        float nsr = fmaf(wre[m], sr[m], fmaf(-wim[m], si[m], uv));
        float nsi = fmaf(wre[m], si[m], wim[m]*sr[m]);
        sr[m] = nsr; si[m] = nsi;
        part = fmaf(okr[m], nsr, fmaf(oki[m], nsi, part));
      }
      part += __shfl_xor(part, 1);
      part += __shfl_xor(part, 2);
      float v = part + uv*Dc;
      res[s] = 0.5f*v*(1.0f + erff(v*0.70710678118f));   // exact gelu
    }
    if (g == 0)
      uw4[(base+q) ^ sw] = make_float4(res[0], res[1], res[2], res[3]);
  }
  __syncthreads();
  float4* dst4 = (float4*)(gout + (size_t)seq*TT);
  for (int i = lane; i < TT/4; i += 64)
    dst4[i] = uw4[i ^ ((i>>6)&7)];
}

// ---------------- fused GEMM: OUT[b] = epilogue(W @ IN[b]) ----------------
// MODE 0: GLU  — W=Wo[2C,C]; computes top rows r and bottom rows C+r; out = (top+bo)*sigmoid(bot+bo')
// MODE 1: PReLU — W=W1[H,C]; out = prelu(acc + b1, aux=prelu_a per row)
// MODE 2: resid — W=W2[C,H]; out = acc + b2 + aux(x residual)
template<int MODE>
__global__ __launch_bounds__(256) void gemm_kernel(
    const float* __restrict__ W, const float* __restrict__ IN,
    const float* __restrict__ bias, const float* __restrict__ aux,
    float* __restrict__ OUT, int K, size_t in_z, size_t out_z, size_t aux_z)
{
  constexpr int BM = 64, BN = 64, BK = 16;
  __shared__ __align__(16) float Ws [BK][BM+4];
  __shared__ __align__(16) float Wsb[BK][BM+4];
  __shared__ __align__(16) float Is [BK][BN];
  IN  += blockIdx.z * in_z;
  OUT += blockIdx.z * out_z;
  const float* auxp = aux;
  if (MODE == 2) auxp = aux + blockIdx.z * aux_z;
  const int tid = threadIdx.x;
  const int tx = tid & 15, ty = tid >> 4;
  const int row0 = blockIdx.y * BM, col0 = blockIdx.x * BN;
  float acc[4][4], accB[4][4];
  #pragma unroll
  for (int i = 0; i < 4; ++i)
    #pragma unroll
    for (int jj = 0; jj < 4; ++jj){ acc[i][jj] = 0.f; accB[i][jj] = 0.f; }

  const int wk = tid & 15;      // k within W tile
  const int wr = tid >> 4;      // row base (16 rows / round)
  const int ic = tid & 63, ik = tid >> 6;

  for (int k0 = 0; k0 < K; k0 += BK){
    #pragma unroll
    for (int it = 0; it < 4; ++it){
      int r = wr + 16*it;
      Ws[wk][r] = W[(size_t)(row0 + r)*K + k0 + wk];
      if (MODE == 0)
        Wsb[wk][r] = W[(size_t)(CC + row0 + r)*K + k0 + wk];
      Is[ik + 4*it][ic] = IN[(size_t)(k0 + ik + 4*it)*TT + col0 + ic];
    }
    __syncthreads();
    #pragma unroll
    for (int kk = 0; kk < BK; ++kk){
      const float4 a  = *(const float4*)&Ws[kk][ty*4];
      const float4 bv = *(const float4*)&Is[kk][tx*4];
      float av[4] = {a.x, a.y, a.z, a.w};
      float bb[4] = {bv.x, bv.y, bv.z, bv.w};
      if (MODE == 0){
        const float4 ab = *(const float4*)&Wsb[kk][ty*4];
        float avb[4] = {ab.x, ab.y, ab.z, ab.w};
        #pragma unroll
        for (int i = 0; i < 4; ++i)
          #pragma unroll
          for (int jj = 0; jj < 4; ++jj){
            acc [i][jj] = fmaf(av [i], bb[jj], acc [i][jj]);
            accB[i][jj] = fmaf(avb[i], bb[jj], accB[i][jj]);
          }
      } else {
        #pragma unroll
        for (int i = 0; i < 4; ++i)
          #pragma unroll
          for (int jj = 0; jj < 4; ++jj)
            acc[i][jj] = fmaf(av[i], bb[jj], acc[i][jj]);
      }
    }
    __syncthreads();
  }

  #pragma unroll
  for (int i = 0; i < 4; ++i){
    int r = row0 + ty*4 + i;
    float ov[4];
    float4 rx;
    if (MODE == 2) rx = *(const float4*)&auxp[(size_t)r*TT + col0 + tx*4];
    #pragma unroll
    for (int jj = 0; jj < 4; ++jj){
      float v = acc[i][jj];
      if (MODE == 0){
        float top = v + bias[r];
        float bot = accB[i][jj] + bias[CC + r];
        ov[jj] = top * (1.0f/(1.0f + expf(-bot)));
      } else if (MODE == 1){
        v += bias[r];
        ov[jj] = (v >= 0.f) ? v : aux[r]*v;
      } else {
        float rr[4] = {rx.x, rx.y, rx.z, rx.w};
        ov[jj] = v + bias[r] + rr[jj];
      }
    }
    *(float4*)&OUT[(size_t)r*TT + col0 + tx*4] = make_float4(ov[0], ov[1], ov[2], ov[3]);
  }
}

// ---------------- host launch ----------------
extern "C" void kernel_launch(void* const* d_in, const int* in_sizes, int n_in,
                              void* d_out, int out_size, void* d_ws, size_t ws_size,
                              hipStream_t stream)
{
  const float* x          = (const float*)d_in[0];
  const float* gamma      = (const float*)d_in[1];
  const float* beta       = (const float*)d_in[2];
  const float* log_dt     = (const float*)d_in[3];
  const float* C_re       = (const float*)d_in[4];
  const float* C_im       = (const float*)d_in[5];
  const float* log_A_real = (const float*)d_in[6];
  const float* A_imag     = (const float*)d_in[7];
  const float* Dp         = (const float*)d_in[8];
  const float* Wo         = (const float*)d_in[9];
  const float* bo         = (const float*)d_in[10];
  const float* W1         = (const float*)d_in[11];
  const float* b1         = (const float*)d_in[12];
  const float* prelu_a    = (const float*)d_in[13];
  const float* W2         = (const float*)d_in[14];
  const float* b2         = (const float*)d_in[15];
  float* out = (float*)d_out;

  const size_t SEG = (size_t)BB*CC*TT;   // 8388608 floats (33.5 MB)
  const size_t CT  = (size_t)CC*TT;      // per-b plane of C x T
  float* u   = (float*)d_ws;             // [B,C,T]
  float* g   = u + SEG;                  // [B,C,T] gelu(S4D out)
  float* h   = u + 2*SEG;                // [H,T] per-b (reused)
  float* glu = u;                        // aliases u (dead after s4d)

  // 1) ChannelwiseLayerNorm
  ln_kernel<<<dim3(BB*(TT/64)), 256, 0, stream>>>(x, gamma, beta, u);
  // 2) S4D recurrence + D-skip + GELU
  s4d_kernel<<<dim3((BB*CC)/4), 256, 0, stream>>>(u, log_dt, C_re, C_im,
                                                  log_A_real, A_imag, Dp, g);
  // 3) 1x1 conv to 2C + GLU (fused, all b)
  gemm_kernel<0><<<dim3(TT/64, CC/64, BB), 256, 0, stream>>>(
      Wo, g, bo, nullptr, glu, CC, CT, CT, 0);
  // 4+5) MLP per b (h buffer reused across b)
  for (int b = 0; b < BB; ++b){
    gemm_kernel<1><<<dim3(TT/64, HH/64, 1), 256, 0, stream>>>(
        W1, glu + (size_t)b*CT, b1, prelu_a, h, CC, 0, 0, 0);
    gemm_kernel<2><<<dim3(TT/64, CC/64, 1), 256, 0, stream>>>(
        W2, h, b2, x + (size_t)b*CT, out + (size_t)b*CT, HH, 0, 0, 0);
  }
}

// Round 2
// 318.922 us; speedup vs baseline: 4.1812x; 4.1812x over previous
//
#include <hip/hip_runtime.h>
#include <math.h>

#define BB 4
#define CC 512
#define TT 4096
#define NN2 32
#define HH 2048

typedef __bf16 bf8v __attribute__((ext_vector_type(8)));
typedef __bf16 bf4v __attribute__((ext_vector_type(4)));
typedef float  f4v  __attribute__((ext_vector_type(4)));
typedef unsigned short u16x8 __attribute__((ext_vector_type(8)));

__device__ __forceinline__ void gload16(const void* g, void* l){
  __builtin_amdgcn_global_load_lds(
      (const __attribute__((address_space(1))) unsigned int*)g,
      (__attribute__((address_space(3))) unsigned int*)l, 16, 0, 0);
}
__device__ __forceinline__ float b2f(unsigned short h){
  union { unsigned int u; float f; } x; x.u = (unsigned int)h << 16; return x.f;
}

// ---------------- ChannelwiseLayerNorm over C of [B, C, T] -> bf16 ----------------
__global__ __launch_bounds__(256) void ln_kernel(
    const float* __restrict__ x, const float* __restrict__ gamma,
    const float* __restrict__ beta, __bf16* __restrict__ u)
{
  int tile = blockIdx.x & (TT/64 - 1);
  int b    = blockIdx.x >> 6;          // TT/64 == 64
  int tl = threadIdx.x & 63;
  int cg = threadIdx.x >> 6;
  int t = tile*64 + tl;
  const float* xp = x + (size_t)b*CC*TT + t;
  float s = 0.f, s2 = 0.f;
  #pragma unroll 4
  for (int c = cg*128; c < (cg+1)*128; ++c){
    float v = xp[(size_t)c*TT];
    s += v; s2 = fmaf(v, v, s2);
  }
  __shared__ float ls[4][64], ls2[4][64], mean_s[64], inv_s[64];
  ls[cg][tl] = s; ls2[cg][tl] = s2;
  __syncthreads();
  if (threadIdx.x < 64){
    float ss  = ls [0][tl]+ls [1][tl]+ls [2][tl]+ls [3][tl];
    float ss2 = ls2[0][tl]+ls2[1][tl]+ls2[2][tl]+ls2[3][tl];
    float mean = ss * (1.f/CC);
    float var  = ss2 * (1.f/CC) - mean*mean;
    mean_s[tl] = mean;
    inv_s[tl]  = rsqrtf(var + 1e-5f);
  }
  __syncthreads();
  float mean = mean_s[tl], inv = inv_s[tl];
  __bf16* up = u + (size_t)b*CC*TT + t;
  #pragma unroll 4
  for (int c = cg*128; c < (cg+1)*128; ++c){
    float v = xp[(size_t)c*TT];
    up[(size_t)c*TT] = (__bf16)fmaf(gamma[c]*inv, v - mean, beta[c]);
  }
}

// ---------------- S4D chunked parallel scan + D-skip + exact GELU (bf16 io) ----------------
__global__ __launch_bounds__(256) void s4d_kernel(
    const __bf16* __restrict__ u, const float* __restrict__ log_dt,
    const float* __restrict__ C_re, const float* __restrict__ C_im,
    const float* __restrict__ log_A_real, const float* __restrict__ A_imag,
    const float* __restrict__ Dp, __bf16* __restrict__ gout)
{
  __shared__ __align__(16) unsigned short us[4][TT];   // 32 KiB
  __shared__ float carry[4][NN2][16][2];               // 16 KiB
  const int tid = threadIdx.x;
  const int wv   = tid >> 6;
  const int lane = tid & 63;
  const int j = lane >> 2;                    // chunk 0..15 (256 steps each)
  const int g = lane & 3;                     // mode group 0..3
  const int seq = blockIdx.x*4 + wv;
  const int b = seq / CC, c = seq % CC;
  (void)b;

  const u16x8* src = (const u16x8*)(u + (size_t)seq*TT);
  u16x8* uw = (u16x8*)us[wv];
  for (int i = lane; i < TT/8; i += 64)
    uw[i ^ ((i>>5)&7)] = src[i];

  float wre[8], wim[8], okr[8], oki[8];
  float dt = expf(log_dt[c]);
  #pragma unroll
  for (int m = 0; m < 8; ++m){
    int n = g*8 + m;
    float Ar = -expf(log_A_real[c*NN2 + n]);
    float Ai = A_imag[c*NN2 + n];
    float er = expf(Ar*dt);
    float sw_, cw_; sincosf(Ai*dt, &sw_, &cw_);
    wre[m] = er*cw_; wim[m] = er*sw_;
    float nr = wre[m] - 1.0f, ni = wim[m];
    float inv = 1.0f/(Ar*Ar + Ai*Ai);
    float qr = (nr*Ar + ni*Ai)*inv;
    float qi = (ni*Ar - nr*Ai)*inv;
    float Cr = C_re[c*NN2 + n], Ci = C_im[c*NN2 + n];
    okr[m] =  2.0f*(Cr*qr - Ci*qi);
    oki[m] = -2.0f*(Cr*qi + Ci*qr);
  }

  // Phase A: local scan from zero
  float sr[8], si[8];
  #pragma unroll
  for (int m = 0; m < 8; ++m){ sr[m]=0.f; si[m]=0.f; }
  for (int q = 0; q < 32; ++q){
    u16x8 v8 = uw[(j*32 + q) ^ (j&7)];
    #pragma unroll
    for (int s = 0; s < 8; ++s){
      float uv = b2f(v8[s]);
      #pragma unroll
      for (int m = 0; m < 8; ++m){
        float nsr = fmaf(wre[m], sr[m], fmaf(-wim[m], si[m], uv));
        float nsi = fmaf(wre[m], si[m], wim[m]*sr[m]);
        sr[m] = nsr; si[m] = nsi;
      }
    }
  }
  #pragma unroll
  for (int m = 0; m < 8; ++m){
    carry[wv][g*8+m][j][0] = sr[m];
    carry[wv][g*8+m][j][1] = si[m];
  }
  __syncthreads();

  // prefix combine across chunks
  if (tid < 4*NN2){
    int sq = tid >> 5, n = tid & 31;
    int cc2 = (blockIdx.x*4 + sq) % CC;
    float dt2 = expf(log_dt[cc2]);
    float Ar = -expf(log_A_real[cc2*NN2 + n]);
    float Ai = A_imag[cc2*NN2 + n];
    float er = expf(Ar*dt2*256.0f);
    float sw_, cw_; sincosf(Ai*dt2*256.0f, &sw_, &cw_);
    float wMr = er*cw_, wMi = er*sw_;
    float Er = 0.f, Ei = 0.f;
    for (int q = 0; q < 16; ++q){
      float cr = carry[sq][n][q][0], ci = carry[sq][n][q][1];
      carry[sq][n][q][0] = Er; carry[sq][n][q][1] = Ei;
      float nEr = cr + wMr*Er - wMi*Ei;
      float nEi = ci + wMr*Ei + wMi*Er;
      Er = nEr; Ei = nEi;
    }
  }
  __syncthreads();

  // Phase B: rescan with corrected init, emit gelu(conv + u*D) as bf16
  #pragma unroll
  for (int m = 0; m < 8; ++m){
    sr[m] = carry[wv][g*8+m][j][0];
    si[m] = carry[wv][g*8+m][j][1];
  }
  float Dc = Dp[c];
  for (int q = 0; q < 32; ++q){
    u16x8 v8 = uw[(j*32 + q) ^ (j&7)];
    u16x8 r8;
    #pragma unroll
    for (int s = 0; s < 8; ++s){
      float uv = b2f(v8[s]);
      float part = 0.f;
      #pragma unroll
      for (int m = 0; m < 8; ++m){
        float nsr = fmaf(wre[m], sr[m], fmaf(-wim[m], si[m], uv));
        float nsi = fmaf(wre[m], si[m], wim[m]*sr[m]);
        sr[m] = nsr; si[m] = nsi;
        part = fmaf(okr[m], nsr, fmaf(oki[m], nsi, part));
      }
      part += __shfl_xor(part, 1);
      part += __shfl_xor(part, 2);
      float v = part + uv*Dc;
      float ge = 0.5f*v*(1.0f + erff(v*0.70710678118f));
      __bf16 hb = (__bf16)ge;
      r8[s] = __builtin_bit_cast(unsigned short, hb);
    }
    if (g == 0)
      uw[(j*32 + q) ^ (j&7)] = r8;
  }
  __syncthreads();
  u16x8* dst = (u16x8*)(gout + (size_t)seq*TT);
  for (int i = lane; i < TT/8; i += 64)
    dst[i] = uw[i ^ ((i>>5)&7)];
}

// ---------------- transpose [B][C][T] bf16 -> [B][T][C] bf16 (64x64 tiles) ----------------
__global__ __launch_bounds__(256) void tr_kernel(const __bf16* __restrict__ gin,
                                                 __bf16* __restrict__ gout)
{
  __shared__ __align__(16) unsigned short ts[64][72];
  int bt = blockIdx.x;           // T/64
  int bc = blockIdx.y;           // C/64
  int b  = blockIdx.z;
  int tid = threadIdx.x;
  const __bf16* gp = gin + ((size_t)b*CC + bc*64)*TT + (size_t)bt*64;
  for (int i = tid; i < 512; i += 256){
    int c = i >> 3, tq = i & 7;
    u16x8 v = *(const u16x8*)(gp + (size_t)c*TT + tq*8);
    #pragma unroll
    for (int s = 0; s < 8; ++s) ts[tq*8+s][c] = v[s];
  }
  __syncthreads();
  __bf16* op = gout + ((size_t)b*TT + bt*64)*CC + bc*64;
  for (int i = tid; i < 512; i += 256){
    int t = i >> 3, cq = i & 7;
    u16x8 v = *(const u16x8*)&ts[t][cq*8];
    *(u16x8*)(op + (size_t)t*CC + cq*8) = v;
  }
}

// ---------------- fp32 -> bf16 weight convert ----------------
__global__ __launch_bounds__(256) void cvt_kernel(const float4* __restrict__ in,
                                                  bf4v* __restrict__ out, int n4)
{
  int i = blockIdx.x*256 + threadIdx.x;
  if (i < n4){
    float4 v = in[i];
    bf4v o; o[0]=(__bf16)v.x; o[1]=(__bf16)v.y; o[2]=(__bf16)v.z; o[3]=(__bf16)v.w;
    out[i] = o;
  }
}

// ---------------- bf16 MFMA GEMM, both operands row-major-K ----------------
// D[m][n] = sum_k Aw[m][k] * Bt[n][k]   (m97 structure: 128x128 tile, BK=32)
// MODE 0: GLU   — Aw=Wo_bf [1024][512]; dual A-tile; out bf16 [tok][C] = top*sigmoid(gate)
// MODE 1: PReLU — Aw=W1_bf [2048][512]; out bf16 [tok][H]
// MODE 2: resid — Aw=h [tok][2048], Bt=W2_bf [512][2048]; out fp32 [b][ch][t] (+b2 +x)
template<int MODE>
__global__ __launch_bounds__(256, 2) void mm_kernel(
    const __bf16* __restrict__ Aw, const __bf16* __restrict__ Bt,
    const float* __restrict__ bias, const float* __restrict__ aux,
    void* __restrict__ outp, int K)
{
  __shared__ __align__(16) __bf16 As[128*32];
  __shared__ __align__(16) __bf16 Bs[128*32];
  __shared__ __align__(16) __bf16 As2[(MODE==0)?128*32:8];

  const int tid = threadIdx.x;
  const int l = tid & 63;
  const int lr = l & 15, kh = l >> 4;
  const int w = tid >> 6;
  const int wr = w >> 1, wc = w & 1;
  const int m0 = blockIdx.y * 128, n0 = blockIdx.x * 128;

  f4v acc[4][4];
  f4v acc2[(MODE==0)?4:1][(MODE==0)?4:1];
  #pragma unroll
  for (int a=0;a<4;++a)
    #pragma unroll
    for (int bq=0;bq<4;++bq)
      #pragma unroll
      for (int r=0;r<4;++r){
        acc[a][bq][r] = 0.f;
        if constexpr (MODE==0) acc2[a][bq][r] = 0.f;
      }

  const char* pA = (const char*)Aw;
  const char* pB = (const char*)Bt;

  for (int k0 = 0; k0 < K; k0 += 32){
    #pragma unroll
    for (int i = 0; i < 2; ++i){
      int cch = i*256 + tid;
      int row = cch >> 2;
      int kb  = (cch & 3) * 16;
      gload16(pA + ((size_t)(m0 + row)*K + k0)*2 + kb, (char*)As + cch*16);
      gload16(pB + ((size_t)(n0 + row)*K + k0)*2 + kb, (char*)Bs + cch*16);
      if constexpr (MODE==0)
        gload16(pA + ((size_t)(CC + m0 + row)*K + k0)*2 + kb, (char*)As2 + cch*16);
    }
    __syncthreads();
    bf8v af[4], bfv[4];
    #pragma unroll
    for (int mi=0;mi<4;++mi)
      af[mi] = *(const bf8v*)&As[(wr*64 + mi*16 + lr)*32 + kh*8];
    #pragma unroll
    for (int ni=0;ni<4;++ni)
      bfv[ni] = *(const bf8v*)&Bs[(wc*64 + ni*16 + lr)*32 + kh*8];
    if constexpr (MODE==0){
      bf8v af2[4];
      #pragma unroll
      for (int mi=0;mi<4;++mi)
        af2[mi] = *(const bf8v*)&As2[(wr*64 + mi*16 + lr)*32 + kh*8];
      #pragma unroll
      for (int mi=0;mi<4;++mi)
        #pragma unroll
        for (int ni=0;ni<4;++ni){
          acc [mi][ni] = __builtin_amdgcn_mfma_f32_16x16x32_bf16(af [mi], bfv[ni], acc [mi][ni], 0,0,0);
          acc2[mi][ni] = __builtin_amdgcn_mfma_f32_16x16x32_bf16(af2[mi], bfv[ni], acc2[mi][ni], 0,0,0);
        }
    } else {
      #pragma unroll
      for (int mi=0;mi<4;++mi)
        #pragma unroll
        for (int ni=0;ni<4;++ni)
          acc[mi][ni] = __builtin_amdgcn_mfma_f32_16x16x32_bf16(af[mi], bfv[ni], acc[mi][ni], 0,0,0);
    }
    __syncthreads();
  }

  if constexpr (MODE==0 || MODE==1){
    const int COUT = (MODE==0) ? CC : HH;
    __bf16* O = (__bf16*)outp;
    #pragma unroll
    for (int mi=0;mi<4;++mi){
      int m = m0 + wr*64 + mi*16 + kh*4;
      float4 bi = *(const float4*)&bias[m];
      float bia[4] = {bi.x, bi.y, bi.z, bi.w};
      float gta[4], paa[4];
      if constexpr (MODE==0){
        float4 bg = *(const float4*)&bias[CC + m];
        gta[0]=bg.x; gta[1]=bg.y; gta[2]=bg.z; gta[3]=bg.w;
      } else {
        float4 pa = *(const float4*)&aux[m];
        paa[0]=pa.x; paa[1]=pa.y; paa[2]=pa.z; paa[3]=pa.w;
      }
      #pragma unroll
      for (int ni=0;ni<4;++ni){
        int tok = n0 + wc*64 + ni*16 + lr;
        bf4v o;
        #pragma unroll
        for (int r=0;r<4;++r){
          float v = acc[mi][ni][r] + bia[r];
          if constexpr (MODE==0){
            float gate = acc2[mi][ni][r] + gta[r];
            v = v * (1.f/(1.f + expf(-gate)));
          } else {
            v = (v >= 0.f) ? v : paa[r]*v;
          }
          o[r] = (__bf16)v;
        }
        *(bf4v*)&O[(size_t)tok*COUT + m] = o;
      }
    }
  } else {
    float* O = (float*)outp;
    #pragma unroll
    for (int mi=0;mi<4;++mi){
      int mrow = m0 + wr*64 + mi*16 + kh*4;   // token within 2-batch slab [0,8192)
      int bl = mrow >> 12, t = mrow & 4095;
      #pragma unroll
      for (int ni=0;ni<4;++ni){
        int ch = n0 + wc*64 + ni*16 + lr;
        size_t base = ((size_t)(bl*CC + ch))*TT + t;
        float4 xr = *(const float4*)&aux[base];
        float bb2 = bias[ch];
        float4 o;
        o.x = acc[mi][ni][0] + bb2 + xr.x;
        o.y = acc[mi][ni][1] + bb2 + xr.y;
        o.z = acc[mi][ni][2] + bb2 + xr.z;
        o.w = acc[mi][ni][3] + bb2 + xr.w;
        *(float4*)&O[base] = o;
      }
    }
  }
}

// ---------------- host launch ----------------
extern "C" void kernel_launch(void* const* d_in, const int* in_sizes, int n_in,
                              void* d_out, int out_size, void* d_ws, size_t ws_size,
                              hipStream_t stream)
{
  const float* x          = (const float*)d_in[0];
  const float* gamma      = (const float*)d_in[1];
  const float* beta       = (const float*)d_in[2];
  const float* log_dt     = (const float*)d_in[3];
  const float* C_re       = (const float*)d_in[4];
  const float* C_im       = (const float*)d_in[5];
  const float* log_A_real = (const float*)d_in[6];
  const float* A_imag     = (const float*)d_in[7];
  const float* Dp         = (const float*)d_in[8];
  const float* Wo         = (const float*)d_in[9];
  const float* bo         = (const float*)d_in[10];
  const float* W1         = (const float*)d_in[11];
  const float* b1         = (const float*)d_in[12];
  const float* prelu_a    = (const float*)d_in[13];
  const float* W2         = (const float*)d_in[14];
  const float* b2         = (const float*)d_in[15];
  float* out = (float*)d_out;

  char* base = (char*)d_ws;
  const size_t SEGB = (size_t)BB*CC*TT*2;        // 16.78 MB (bf16 plane)
  __bf16* u_bf  = (__bf16*)(base);               // [B][C][T]
  __bf16* g_cm  = (__bf16*)(base + SEGB);        // [B][C][T]  (later aliased by glu)
  __bf16* g_tm  = (__bf16*)(base + 2*SEGB);      // [B*T][C]
  __bf16* glu   = g_cm;                          // [B*T][C]  (g_cm dead after tr)
  __bf16* h     = (__bf16*)(base + 3*SEGB);      // [8192][H] per 2-batch (33.55 MB)
  __bf16* Wo_bf = (__bf16*)(base + 3*SEGB + (size_t)2*TT*HH*2);
  __bf16* W1_bf = Wo_bf + (size_t)2*CC*CC;
  __bf16* W2_bf = W1_bf + (size_t)HH*CC;

  // weight converts
  cvt_kernel<<<dim3((2*CC*CC/4 + 255)/256), 256, 0, stream>>>((const float4*)Wo, (bf4v*)Wo_bf, 2*CC*CC/4);
  cvt_kernel<<<dim3((HH*CC/4 + 255)/256), 256, 0, stream>>>((const float4*)W1, (bf4v*)W1_bf, HH*CC/4);
  cvt_kernel<<<dim3((CC*HH/4 + 255)/256), 256, 0, stream>>>((const float4*)W2, (bf4v*)W2_bf, CC*HH/4);

  // 1) LayerNorm -> bf16
  ln_kernel<<<dim3(BB*(TT/64)), 256, 0, stream>>>(x, gamma, beta, u_bf);
  // 2) S4D scan + GELU -> bf16 channel-major
  s4d_kernel<<<dim3((BB*CC)/4), 256, 0, stream>>>(u_bf, log_dt, C_re, C_im,
                                                  log_A_real, A_imag, Dp, g_cm);
  // 3) transpose to token-major
  tr_kernel<<<dim3(TT/64, CC/64, BB), 256, 0, stream>>>(g_cm, g_tm);
  // 4) GLU projection (all batches): [16384 tok] x [512 m], K=512
  mm_kernel<0><<<dim3((BB*TT)/128, CC/128), 256, 0, stream>>>(
      Wo_bf, g_tm, bo, nullptr, (void*)glu, CC);
  // 5+6) MLP per 2-batch slab
  for (int bb = 0; bb < 2; ++bb){
    const __bf16* glu_s = glu + (size_t)bb*2*TT*CC;
    mm_kernel<1><<<dim3((2*TT)/128, HH/128), 256, 0, stream>>>(
        W1_bf, glu_s, b1, prelu_a, (void*)h, CC);
    mm_kernel<2><<<dim3(CC/128, (2*TT)/128), 256, 0, stream>>>(
        h, W2_bf, b2, x + (size_t)bb*2*CC*TT, (void*)(out + (size_t)bb*2*CC*TT), HH);
  }
}

// Round 3
// 293.910 us; speedup vs baseline: 4.5371x; 1.0851x over previous
//
#include <hip/hip_runtime.h>
#include <math.h>

#define BB 4
#define CC 512
#define TT 4096
#define NN2 32
#define HH 2048

typedef __bf16 bf8v __attribute__((ext_vector_type(8)));
typedef __bf16 bf4v __attribute__((ext_vector_type(4)));
typedef float  f4v  __attribute__((ext_vector_type(4)));
typedef unsigned short u16x8 __attribute__((ext_vector_type(8)));

__device__ __forceinline__ void gload16(const void* g, void* l){
  __builtin_amdgcn_global_load_lds(
      (const __attribute__((address_space(1))) unsigned int*)g,
      (__attribute__((address_space(3))) unsigned int*)l, 16, 0, 0);
}
__device__ __forceinline__ float b2f(unsigned short h){
  union { unsigned int u; float f; } x; x.u = (unsigned int)h << 16; return x.f;
}
__device__ __forceinline__ float fast_gelu(float v){
  // tanh-form gelu via v_exp_f32; max |err| vs exact ~3e-3
  float x2 = v*v;
  float x  = 0.7978845608f*v*fmaf(0.044715f, x2, 1.0f);
  float t  = __expf(2.0f*x);                     // e^{2x}
  return v - v*__builtin_amdgcn_rcpf(1.0f + t);  // v*t/(1+t), inf-safe
}
__device__ __forceinline__ float fast_sigmoid(float g){
  return __builtin_amdgcn_rcpf(1.0f + __expf(-g));
}

// ---------------- ChannelwiseLayerNorm over C of [B, C, T] -> bf16 ----------------
__global__ __launch_bounds__(256) void ln_kernel(
    const float* __restrict__ x, const float* __restrict__ gamma,
    const float* __restrict__ beta, __bf16* __restrict__ u)
{
  int tile = blockIdx.x & (TT/64 - 1);
  int b    = blockIdx.x >> 6;          // TT/64 == 64
  int tl = threadIdx.x & 63;
  int cg = threadIdx.x >> 6;
  int t = tile*64 + tl;
  const float* xp = x + (size_t)b*CC*TT + t;
  float s = 0.f, s2 = 0.f;
  #pragma unroll 4
  for (int c = cg*128; c < (cg+1)*128; ++c){
    float v = xp[(size_t)c*TT];
    s += v; s2 = fmaf(v, v, s2);
  }
  __shared__ float ls[4][64], ls2[4][64], mean_s[64], inv_s[64];
  ls[cg][tl] = s; ls2[cg][tl] = s2;
  __syncthreads();
  if (threadIdx.x < 64){
    float ss  = ls [0][tl]+ls [1][tl]+ls [2][tl]+ls [3][tl];
    float ss2 = ls2[0][tl]+ls2[1][tl]+ls2[2][tl]+ls2[3][tl];
    float mean = ss * (1.f/CC);
    float var  = ss2 * (1.f/CC) - mean*mean;
    mean_s[tl] = mean;
    inv_s[tl]  = rsqrtf(var + 1e-5f);
  }
  __syncthreads();
  float mean = mean_s[tl], inv = inv_s[tl];
  __bf16* up = u + (size_t)b*CC*TT + t;
  #pragma unroll 4
  for (int c = cg*128; c < (cg+1)*128; ++c){
    float v = xp[(size_t)c*TT];
    up[(size_t)c*TT] = (__bf16)fmaf(gamma[c]*inv, v - mean, beta[c]);
  }
}

// ---------------- S4D chunked parallel scan + D-skip + GELU (bf16 io) ----------------
// 2 sequences per 256-block; 2 waves per sequence. Per seq: 32 chunks of 128
// steps x 4 mode-groups of 8. Two-pass scan with w^128 prefix combine.
__global__ __launch_bounds__(256, 4) void s4d_kernel(
    const __bf16* __restrict__ u, const float* __restrict__ log_dt,
    const float* __restrict__ C_re, const float* __restrict__ C_im,
    const float* __restrict__ log_A_real, const float* __restrict__ A_imag,
    const float* __restrict__ Dp, __bf16* __restrict__ gout)
{
  __shared__ __align__(16) unsigned short us[2][TT];   // 16 KiB
  __shared__ float carry[2][NN2][33][2];               // ~16.9 KiB (pad 33)
  const int tid = threadIdx.x;
  const int wv   = tid >> 6;
  const int sq   = wv >> 1;                   // sequence slot 0..1
  const int wh   = wv & 1;                    // chunk half
  const int lane = tid & 63;
  const int jl = lane >> 2;
  const int j  = wh*16 + jl;                  // chunk 0..31 (128 steps each)
  const int g  = lane & 3;                    // mode group 0..3
  const int seq = blockIdx.x*2 + sq;
  const int c = seq % CC;

  // cooperative swizzled load of u[seq,:] into LDS (both waves of this seq)
  const u16x8* src = (const u16x8*)(u + (size_t)seq*TT);
  u16x8* uw = (u16x8*)us[sq];
  for (int i = wh*64 + lane; i < TT/8; i += 128)
    uw[i ^ ((i>>4)&7)] = src[i];

  float wre[8], wim[8], okr[8], oki[8];
  float dt = expf(log_dt[c]);
  #pragma unroll
  for (int m = 0; m < 8; ++m){
    int n = g*8 + m;
    float Ar = -expf(log_A_real[c*NN2 + n]);
    float Ai = A_imag[c*NN2 + n];
    float er = expf(Ar*dt);
    float sw_, cw_; sincosf(Ai*dt, &sw_, &cw_);
    wre[m] = er*cw_; wim[m] = er*sw_;
    float nr = wre[m] - 1.0f, ni = wim[m];
    float inv = 1.0f/(Ar*Ar + Ai*Ai);
    float qr = (nr*Ar + ni*Ai)*inv;
    float qi = (ni*Ar - nr*Ai)*inv;
    float Cr = C_re[c*NN2 + n], Ci = C_im[c*NN2 + n];
    okr[m] =  2.0f*(Cr*qr - Ci*qi);
    oki[m] = -2.0f*(Cr*qi + Ci*qr);
  }
  __syncthreads();

  // Phase A: local scan from zero (128 steps)
  float sr[8], si[8];
  #pragma unroll
  for (int m = 0; m < 8; ++m){ sr[m]=0.f; si[m]=0.f; }
  const int vbase = j*16, sw = j & 7;
  for (int q = 0; q < 16; ++q){
    u16x8 v8 = uw[(vbase + q) ^ sw];
    #pragma unroll
    for (int s = 0; s < 8; ++s){
      float uv = b2f(v8[s]);
      #pragma unroll
      for (int m = 0; m < 8; ++m){
        float nsr = fmaf(wre[m], sr[m], fmaf(-wim[m], si[m], uv));
        float nsi = fmaf(wre[m], si[m], wim[m]*sr[m]);
        sr[m] = nsr; si[m] = nsi;
      }
    }
  }
  #pragma unroll
  for (int m = 0; m < 8; ++m){
    carry[sq][g*8+m][j][0] = sr[m];
    carry[sq][g*8+m][j][1] = si[m];
  }
  __syncthreads();

  // prefix combine across 32 chunks: 64 (seq,mode) pairs
  if (tid < 2*NN2){
    int sq2 = tid >> 5, n = tid & 31;
    int cc2 = (blockIdx.x*2 + sq2) % CC;
    float dt2 = expf(log_dt[cc2]);
    float Ar = -expf(log_A_real[cc2*NN2 + n]);
    float Ai = A_imag[cc2*NN2 + n];
    float er = expf(Ar*dt2*128.0f);
    float sw_, cw_; sincosf(Ai*dt2*128.0f, &sw_, &cw_);
    float wMr = er*cw_, wMi = er*sw_;
    float Er = 0.f, Ei = 0.f;
    for (int q = 0; q < 32; ++q){
      float cr = carry[sq2][n][q][0], ci = carry[sq2][n][q][1];
      carry[sq2][n][q][0] = Er; carry[sq2][n][q][1] = Ei;
      float nEr = cr + wMr*Er - wMi*Ei;
      float nEi = ci + wMr*Ei + wMi*Er;
      Er = nEr; Ei = nEi;
    }
  }
  __syncthreads();

  // Phase B: rescan with corrected init, emit gelu(conv + u*D) as bf16
  #pragma unroll
  for (int m = 0; m < 8; ++m){
    sr[m] = carry[sq][g*8+m][j][0];
    si[m] = carry[sq][g*8+m][j][1];
  }
  float Dc = Dp[c];
  for (int q = 0; q < 16; ++q){
    u16x8 v8 = uw[(vbase + q) ^ sw];
    u16x8 r8;
    #pragma unroll
    for (int s = 0; s < 8; ++s){
      float uv = b2f(v8[s]);
      float part = 0.f;
      #pragma unroll
      for (int m = 0; m < 8; ++m){
        float nsr = fmaf(wre[m], sr[m], fmaf(-wim[m], si[m], uv));
        float nsi = fmaf(wre[m], si[m], wim[m]*sr[m]);
        sr[m] = nsr; si[m] = nsi;
        part = fmaf(okr[m], nsr, fmaf(oki[m], nsi, part));
      }
      part += __shfl_xor(part, 1);
      part += __shfl_xor(part, 2);
      float v = part + uv*Dc;
      __bf16 hb = (__bf16)fast_gelu(v);
      r8[s] = __builtin_bit_cast(unsigned short, hb);
    }
    if (g == 0)
      uw[(vbase + q) ^ sw] = r8;
  }
  __syncthreads();
  u16x8* dst = (u16x8*)(gout + (size_t)seq*TT);
  for (int i = wh*64 + lane; i < TT/8; i += 128)
    dst[i] = uw[i ^ ((i>>4)&7)];
}

// ---------------- transpose [B][C][T] bf16 -> [B][T][C] bf16 (64x64 tiles) ----------------
__global__ __launch_bounds__(256) void tr_kernel(const __bf16* __restrict__ gin,
                                                 __bf16* __restrict__ gout)
{
  __shared__ __align__(16) unsigned short ts[64][72];
  int bt = blockIdx.x;           // T/64
  int bc = blockIdx.y;           // C/64
  int b  = blockIdx.z;
  int tid = threadIdx.x;
  const __bf16* gp = gin + ((size_t)b*CC + bc*64)*TT + (size_t)bt*64;
  for (int i = tid; i < 512; i += 256){
    int c = i >> 3, tq = i & 7;
    u16x8 v = *(const u16x8*)(gp + (size_t)c*TT + tq*8);
    #pragma unroll
    for (int s = 0; s < 8; ++s) ts[tq*8+s][c] = v[s];
  }
  __syncthreads();
  __bf16* op = gout + ((size_t)b*TT + bt*64)*CC + bc*64;
  for (int i = tid; i < 512; i += 256){
    int t = i >> 3, cq = i & 7;
    u16x8 v = *(const u16x8*)&ts[t][cq*8];
    *(u16x8*)(op + (size_t)t*CC + cq*8) = v;
  }
}

// ---------------- fp32 -> bf16 weight convert ----------------
__global__ __launch_bounds__(256) void cvt_kernel(const float4* __restrict__ in,
                                                  bf4v* __restrict__ out, int n4)
{
  int i = blockIdx.x*256 + threadIdx.x;
  if (i < n4){
    float4 v = in[i];
    bf4v o; o[0]=(__bf16)v.x; o[1]=(__bf16)v.y; o[2]=(__bf16)v.z; o[3]=(__bf16)v.w;
    out[i] = o;
  }
}

// ---------------- bf16 MFMA GEMM, both operands row-major-K ----------------
// D[m][n] = sum_k Aw[m][k] * Bt[n][k]   (m97 structure: 128x128 tile, BK=32)
// MODE 0: GLU   — Aw=Wo_bf [1024][512]; dual A-tile; out bf16 [tok][C]
// MODE 1: PReLU — Aw=W1_bf [2048][512]; out bf16 [tok][H]
// MODE 2: resid — Aw=h [tok][2048], Bt=W2_bf [512][2048]; out fp32 [b][ch][t]
template<int MODE>
__global__ __launch_bounds__(256, 2) void mm_kernel(
    const __bf16* __restrict__ Aw, const __bf16* __restrict__ Bt,
    const float* __restrict__ bias, const float* __restrict__ aux,
    void* __restrict__ outp, int K)
{
  __shared__ __align__(16) __bf16 As[128*32];
  __shared__ __align__(16) __bf16 Bs[128*32];
  __shared__ __align__(16) __bf16 As2[(MODE==0)?128*32:8];

  const int tid = threadIdx.x;
  const int l = tid & 63;
  const int lr = l & 15, kh = l >> 4;
  const int w = tid >> 6;
  const int wr = w >> 1, wc = w & 1;
  const int m0 = blockIdx.y * 128, n0 = blockIdx.x * 128;

  f4v acc[4][4];
  f4v acc2[(MODE==0)?4:1][(MODE==0)?4:1];
  #pragma unroll
  for (int a=0;a<4;++a)
    #pragma unroll
    for (int bq=0;bq<4;++bq)
      #pragma unroll
      for (int r=0;r<4;++r){
        acc[a][bq][r] = 0.f;
        if constexpr (MODE==0) acc2[a][bq][r] = 0.f;
      }

  const char* pA = (const char*)Aw;
  const char* pB = (const char*)Bt;

  for (int k0 = 0; k0 < K; k0 += 32){
    #pragma unroll
    for (int i = 0; i < 2; ++i){
      int cch = i*256 + tid;
      int row = cch >> 2;
      int kb  = (cch & 3) * 16;
      gload16(pA + ((size_t)(m0 + row)*K + k0)*2 + kb, (char*)As + cch*16);
      gload16(pB + ((size_t)(n0 + row)*K + k0)*2 + kb, (char*)Bs + cch*16);
      if constexpr (MODE==0)
        gload16(pA + ((size_t)(CC + m0 + row)*K + k0)*2 + kb, (char*)As2 + cch*16);
    }
    __syncthreads();
    bf8v af[4], bfv[4];
    #pragma unroll
    for (int mi=0;mi<4;++mi)
      af[mi] = *(const bf8v*)&As[(wr*64 + mi*16 + lr)*32 + kh*8];
    #pragma unroll
    for (int ni=0;ni<4;++ni)
      bfv[ni] = *(const bf8v*)&Bs[(wc*64 + ni*16 + lr)*32 + kh*8];
    if constexpr (MODE==0){
      bf8v af2[4];
      #pragma unroll
      for (int mi=0;mi<4;++mi)
        af2[mi] = *(const bf8v*)&As2[(wr*64 + mi*16 + lr)*32 + kh*8];
      #pragma unroll
      for (int mi=0;mi<4;++mi)
        #pragma unroll
        for (int ni=0;ni<4;++ni){
          acc [mi][ni] = __builtin_amdgcn_mfma_f32_16x16x32_bf16(af [mi], bfv[ni], acc [mi][ni], 0,0,0);
          acc2[mi][ni] = __builtin_amdgcn_mfma_f32_16x16x32_bf16(af2[mi], bfv[ni], acc2[mi][ni], 0,0,0);
        }
    } else {
      #pragma unroll
      for (int mi=0;mi<4;++mi)
        #pragma unroll
        for (int ni=0;ni<4;++ni)
          acc[mi][ni] = __builtin_amdgcn_mfma_f32_16x16x32_bf16(af[mi], bfv[ni], acc[mi][ni], 0,0,0);
    }
    __syncthreads();
  }

  if constexpr (MODE==0 || MODE==1){
    const int COUT = (MODE==0) ? CC : HH;
    __bf16* O = (__bf16*)outp;
    #pragma unroll
    for (int mi=0;mi<4;++mi){
      int m = m0 + wr*64 + mi*16 + kh*4;
      float4 bi = *(const float4*)&bias[m];
      float bia[4] = {bi.x, bi.y, bi.z, bi.w};
      float gta[4], paa[4];
      if constexpr (MODE==0){
        float4 bg = *(const float4*)&bias[CC + m];
        gta[0]=bg.x; gta[1]=bg.y; gta[2]=bg.z; gta[3]=bg.w;
      } else {
        float4 pa = *(const float4*)&aux[m];
        paa[0]=pa.x; paa[1]=pa.y; paa[2]=pa.z; paa[3]=pa.w;
      }
      #pragma unroll
      for (int ni=0;ni<4;++ni){
        int tok = n0 + wc*64 + ni*16 + lr;
        bf4v o;
        #pragma unroll
        for (int r=0;r<4;++r){
          float v = acc[mi][ni][r] + bia[r];
          if constexpr (MODE==0){
            float gate = acc2[mi][ni][r] + gta[r];
            v = v * fast_sigmoid(gate);
          } else {
            v = (v >= 0.f) ? v : paa[r]*v;
          }
          o[r] = (__bf16)v;
        }
        *(bf4v*)&O[(size_t)tok*COUT + m] = o;
      }
    }
  } else {
    float* O = (float*)outp;
    #pragma unroll
    for (int mi=0;mi<4;++mi){
      int mrow = m0 + wr*64 + mi*16 + kh*4;   // token within 2-batch slab
      int bl = mrow >> 12, t = mrow & 4095;
      #pragma unroll
      for (int ni=0;ni<4;++ni){
        int ch = n0 + wc*64 + ni*16 + lr;
        size_t base = ((size_t)(bl*CC + ch))*TT + t;
        float4 xr = *(const float4*)&aux[base];
        float bb2 = bias[ch];
        float4 o;
        o.x = acc[mi][ni][0] + bb2 + xr.x;
        o.y = acc[mi][ni][1] + bb2 + xr.y;
        o.z = acc[mi][ni][2] + bb2 + xr.z;
        o.w = acc[mi][ni][3] + bb2 + xr.w;
        *(float4*)&O[base] = o;
      }
    }
  }
}

// ---------------- host launch ----------------
extern "C" void kernel_launch(void* const* d_in, const int* in_sizes, int n_in,
                              void* d_out, int out_size, void* d_ws, size_t ws_size,
                              hipStream_t stream)
{
  const float* x          = (const float*)d_in[0];
  const float* gamma      = (const float*)d_in[1];
  const float* beta       = (const float*)d_in[2];
  const float* log_dt     = (const float*)d_in[3];
  const float* C_re       = (const float*)d_in[4];
  const float* C_im       = (const float*)d_in[5];
  const float* log_A_real = (const float*)d_in[6];
  const float* A_imag     = (const float*)d_in[7];
  const float* Dp         = (const float*)d_in[8];
  const float* Wo         = (const float*)d_in[9];
  const float* bo         = (const float*)d_in[10];
  const float* W1         = (const float*)d_in[11];
  const float* b1         = (const float*)d_in[12];
  const float* prelu_a    = (const float*)d_in[13];
  const float* W2         = (const float*)d_in[14];
  const float* b2         = (const float*)d_in[15];
  float* out = (float*)d_out;

  char* base = (char*)d_ws;
  const size_t SEGB = (size_t)BB*CC*TT*2;        // 16.78 MB (bf16 plane)
  __bf16* u_bf  = (__bf16*)(base);               // [B][C][T]
  __bf16* g_cm  = (__bf16*)(base + SEGB);        // [B][C][T]
  __bf16* g_tm  = (__bf16*)(base + 2*SEGB);      // [B*T][C]
  __bf16* glu   = g_cm;                          // aliases (g_cm dead after tr)
  __bf16* h     = (__bf16*)(base + 3*SEGB);      // [8192][H] per 2-batch
  __bf16* Wo_bf = (__bf16*)(base + 3*SEGB + (size_t)2*TT*HH*2);
  __bf16* W1_bf = Wo_bf + (size_t)2*CC*CC;
  __bf16* W2_bf = W1_bf + (size_t)HH*CC;

  cvt_kernel<<<dim3((2*CC*CC/4 + 255)/256), 256, 0, stream>>>((const float4*)Wo, (bf4v*)Wo_bf, 2*CC*CC/4);
  cvt_kernel<<<dim3((HH*CC/4 + 255)/256), 256, 0, stream>>>((const float4*)W1, (bf4v*)W1_bf, HH*CC/4);
  cvt_kernel<<<dim3((CC*HH/4 + 255)/256), 256, 0, stream>>>((const float4*)W2, (bf4v*)W2_bf, CC*HH/4);

  ln_kernel<<<dim3(BB*(TT/64)), 256, 0, stream>>>(x, gamma, beta, u_bf);
  s4d_kernel<<<dim3((BB*CC)/2), 256, 0, stream>>>(u_bf, log_dt, C_re, C_im,
                                                  log_A_real, A_imag, Dp, g_cm);
  tr_kernel<<<dim3(TT/64, CC/64, BB), 256, 0, stream>>>(g_cm, g_tm);
  mm_kernel<0><<<dim3((BB*TT)/128, CC/128), 256, 0, stream>>>(
      Wo_bf, g_tm, bo, nullptr, (void*)glu, CC);
  for (int bb = 0; bb < 2; ++bb){
    const __bf16* glu_s = glu + (size_t)bb*2*TT*CC;
    mm_kernel<1><<<dim3((2*TT)/128, HH/128), 256, 0, stream>>>(
        W1_bf, glu_s, b1, prelu_a, (void*)h, CC);
    mm_kernel<2><<<dim3(CC/128, (2*TT)/128), 256, 0, stream>>>(
        h, W2_bf, b2, x + (size_t)bb*2*CC*TT, (void*)(out + (size_t)bb*2*CC*TT), HH);
  }
}

// Round 4
// 251.862 us; speedup vs baseline: 5.2945x; 1.1669x over previous
//
#include <hip/hip_runtime.h>
#include <math.h>

#define BB 4
#define CC 512
#define TT 4096
#define NN2 32
#define HH 2048

typedef __bf16 bf8v __attribute__((ext_vector_type(8)));
typedef __bf16 bf4v __attribute__((ext_vector_type(4)));
typedef float  f4v  __attribute__((ext_vector_type(4)));
typedef unsigned short u16x8 __attribute__((ext_vector_type(8)));

__device__ __forceinline__ void gload16(const void* g, void* l){
  __builtin_amdgcn_global_load_lds(
      (const __attribute__((address_space(1))) unsigned int*)g,
      (__attribute__((address_space(3))) unsigned int*)l, 16, 0, 0);
}
__device__ __forceinline__ float fast_gelu(float v){
  float x2 = v*v;
  float x  = 0.7978845608f*v*fmaf(0.044715f, x2, 1.0f);
  float t  = __expf(2.0f*x);
  return v - v*__builtin_amdgcn_rcpf(1.0f + t);
}
__device__ __forceinline__ float fast_sigmoid(float g){
  return __builtin_amdgcn_rcpf(1.0f + __expf(-g));
}
__device__ __forceinline__ unsigned short bfbits(float v){
  __bf16 h = (__bf16)v;
  return __builtin_bit_cast(unsigned short, h);
}

// ---------------- ChannelwiseLayerNorm over C of [B, C, T] -> bf16 ----------------
__global__ __launch_bounds__(256) void ln_kernel(
    const float* __restrict__ x, const float* __restrict__ gamma,
    const float* __restrict__ beta, __bf16* __restrict__ u)
{
  int tile = blockIdx.x & (TT/64 - 1);
  int b    = blockIdx.x >> 6;
  int tl = threadIdx.x & 63;
  int cg = threadIdx.x >> 6;
  int t = tile*64 + tl;
  const float* xp = x + (size_t)b*CC*TT + t;
  float s = 0.f, s2 = 0.f;
  #pragma unroll 4
  for (int c = cg*128; c < (cg+1)*128; ++c){
    float v = xp[(size_t)c*TT];
    s += v; s2 = fmaf(v, v, s2);
  }
  __shared__ float ls[4][64], ls2[4][64], mean_s[64], inv_s[64];
  ls[cg][tl] = s; ls2[cg][tl] = s2;
  __syncthreads();
  if (threadIdx.x < 64){
    float ss  = ls [0][tl]+ls [1][tl]+ls [2][tl]+ls [3][tl];
    float ss2 = ls2[0][tl]+ls2[1][tl]+ls2[2][tl]+ls2[3][tl];
    float mean = ss * (1.f/CC);
    float var  = ss2 * (1.f/CC) - mean*mean;
    mean_s[tl] = mean;
    inv_s[tl]  = rsqrtf(var + 1e-5f);
  }
  __syncthreads();
  float mean = mean_s[tl], inv = inv_s[tl];
  __bf16* up = u + (size_t)b*CC*TT + t;
  #pragma unroll 4
  for (int c = cg*128; c < (cg+1)*128; ++c){
    float v = xp[(size_t)c*TT];
    up[(size_t)c*TT] = (__bf16)fmaf(gamma[c]*inv, v - mean, beta[c]);
  }
}

// ---------------- build per-channel S4D basis matrices (bf16) ----------------
// Tt[c][n][k] = KK[n-k] (n>=k, else 0), KK[0] += D      (local Toeplitz conv)
// V [c][2m][k]   = Re(w^(63-k)),  V[c][2m+1][k] = Im(w^(63-k))   (chunk-end state)
// B2[c][n][2m]   = okr*Re(w^(n+1)) + oki*Im(w^(n+1))  (P)
// B2[c][n][2m+1] = oki*Re(w^(n+1)) - okr*Im(w^(n+1))  (Q)       (carry correction)
__global__ __launch_bounds__(256) void build_mats(
    const float* __restrict__ log_dt, const float* __restrict__ C_re,
    const float* __restrict__ C_im, const float* __restrict__ log_A_real,
    const float* __restrict__ A_imag, const float* __restrict__ Dp,
    __bf16* __restrict__ Tt, __bf16* __restrict__ V, __bf16* __restrict__ B2)
{
  __shared__ float cpart[4][64][33];
  __shared__ float kk[4][65];
  const int wv = threadIdx.x >> 6, lane = threadIdx.x & 63;
  const int c = blockIdx.x*4 + wv;
  const int m = lane & 31;
  float dt = expf(log_dt[c]);
  float Ar = -expf(log_A_real[c*NN2+m]);
  float Ai = A_imag[c*NN2+m];
  float er = expf(Ar*dt);
  float sw_, cw_; sincosf(Ai*dt, &sw_, &cw_);
  float wre = er*cw_, wim = er*sw_;
  float nr = wre-1.f, ni = wim;
  float inv = 1.f/(Ar*Ar + Ai*Ai);
  float qr = (nr*Ar + ni*Ai)*inv;
  float qi = (ni*Ar - nr*Ai)*inv;
  float Cr = C_re[c*NN2+m], Ci = C_im[c*NN2+m];
  float okr =  2.f*(Cr*qr - Ci*qi);
  float oki = -2.f*(Cr*qi + Ci*qr);
  __bf16* Ttc = Tt + (size_t)c*4096;
  __bf16* Vc  = V  + (size_t)c*4096;
  __bf16* B2c = B2 + (size_t)c*4096;
  if (lane < 32){
    float pre = 1.f, pim = 0.f;
    for (int l = 0; l <= 64; ++l){
      if (l <= 63){
        Vc[(2*m)*64   + (63-l)] = (__bf16)pre;
        Vc[(2*m+1)*64 + (63-l)] = (__bf16)pim;
      }
      float cR = fmaf(okr, pre,  oki*pim);
      float cQ = fmaf(oki, pre, -okr*pim);
      if (l <= 63) cpart[wv][l][m] = cR;
      if (l >= 1){
        B2c[(l-1)*64 + 2*m]   = (__bf16)cR;
        B2c[(l-1)*64 + 2*m+1] = (__bf16)cQ;
      }
      float npre = wre*pre - wim*pim;
      float npim = wre*pim + wim*pre;
      pre = npre; pim = npim;
    }
  }
  __syncthreads();
  float s = 0.f;
  #pragma unroll
  for (int mm = 0; mm < 32; ++mm) s += cpart[wv][lane][mm];
  if (lane == 0) s += Dp[c];
  kk[wv][lane] = s;
  __syncthreads();
  const int n = lane;
  #pragma unroll
  for (int kb = 0; kb < 8; ++kb){
    u16x8 v;
    #pragma unroll
    for (int e = 0; e < 8; ++e){
      int k = kb*8 + e;
      v[e] = bfbits((n >= k) ? kk[wv][n-k] : 0.f);
    }
    *(u16x8*)&Ttc[n*64 + kb*8] = v;
  }
}

// ---------------- fused S4D via MFMA: G=U@V -> scan -> Y=U@Tt+S0@B2 -> gelu ----------------
// One wave per sequence (b,c); 2 waves per 128-thread block.
// U = u[seq] reshaped [64 chunks][64 steps]; all matmuls 64x64x64 bf16 MFMA.
__global__ __launch_bounds__(128) void s4dm_kernel(
    const __bf16* __restrict__ u, const float* __restrict__ log_dt,
    const float* __restrict__ log_A_real, const float* __restrict__ A_imag,
    const __bf16* __restrict__ Tt, const __bf16* __restrict__ V,
    const __bf16* __restrict__ B2, __bf16* __restrict__ gout)
{
  __shared__ __align__(16) float gbuf[2][64][66];            // 33.8 KiB
  __shared__ __align__(16) unsigned short s0buf[2][64][72];  // 18.4 KiB
  const int wv = threadIdx.x >> 6, l = threadIdx.x & 63;
  const int lr = l & 15, q = l >> 4;
  const int seq = blockIdx.x*2 + wv;
  const int c = seq & (CC-1);
  const __bf16* Up  = u  + (size_t)seq*TT;
  const __bf16* Ttc = Tt + (size_t)c*4096;
  const __bf16* Vc  = V  + (size_t)c*4096;
  const __bf16* B2c = B2 + (size_t)c*4096;

  f4v acc[4][4];
  #pragma unroll
  for (int a=0;a<4;++a)
    #pragma unroll
    for (int b=0;b<4;++b)
      #pragma unroll
      for (int r=0;r<4;++r) acc[a][b][r] = 0.f;

  // ---- G = U @ V ----
  #pragma unroll
  for (int kw = 0; kw < 2; ++kw){
    bf8v af[4], bv[4];
    #pragma unroll
    for (int mt=0;mt<4;++mt)
      af[mt] = *(const bf8v*)(Up + (mt*16+lr)*64 + kw*32 + q*8);
    #pragma unroll
    for (int nt=0;nt<4;++nt)
      bv[nt] = *(const bf8v*)(Vc + (nt*16+lr)*64 + kw*32 + q*8);
    #pragma unroll
    for (int mt=0;mt<4;++mt)
      #pragma unroll
      for (int nt=0;nt<4;++nt)
        acc[mt][nt] = __builtin_amdgcn_mfma_f32_16x16x32_bf16(af[mt], bv[nt], acc[mt][nt], 0,0,0);
  }
  #pragma unroll
  for (int mt=0;mt<4;++mt)
    #pragma unroll
    for (int nt=0;nt<4;++nt)
      #pragma unroll
      for (int r=0;r<4;++r)
        gbuf[wv][mt*16 + q*4 + r][nt*16 + lr] = acc[mt][nt][r];
  __syncthreads();

  // ---- carry scan over 64 chunks (lanes 0..31, one complex mode each) ----
  if (l < 32){
    const int m = l;
    float dt = expf(log_dt[c]);
    float Ar = -expf(log_A_real[c*NN2+m]);
    float Ai = A_imag[c*NN2+m];
    float er = expf(Ar*dt);
    float sw_, cw_; sincosf(Ai*dt, &sw_, &cw_);
    float wr_ = er*cw_, wi_ = er*sw_;
    #pragma unroll
    for (int sq2=0;sq2<6;++sq2){           // w^64 by repeated squaring
      float a=wr_, b=wi_;
      wr_ = a*a - b*b; wi_ = 2.f*a*b;
    }
    float S0r=0.f, S0i=0.f;
    for (int j=0;j<64;++j){
      float gr = gbuf[wv][j][2*m], gi = gbuf[wv][j][2*m+1];
      s0buf[wv][j][2*m]   = bfbits(S0r);
      s0buf[wv][j][2*m+1] = bfbits(S0i);
      float nRe = fmaf(wr_, S0r, fmaf(-wi_, S0i, gr));
      float nIm = fmaf(wr_, S0i, fmaf( wi_, S0r, gi));
      S0r = nRe; S0i = nIm;
    }
  }
  __syncthreads();

  // ---- Y = U @ Tt + S0 @ B2 ----
  #pragma unroll
  for (int a=0;a<4;++a)
    #pragma unroll
    for (int b=0;b<4;++b)
      #pragma unroll
      for (int r=0;r<4;++r) acc[a][b][r] = 0.f;
  #pragma unroll
  for (int kw = 0; kw < 2; ++kw){
    bf8v af[4], bv[4];
    #pragma unroll
    for (int mt=0;mt<4;++mt)
      af[mt] = *(const bf8v*)(Up + (mt*16+lr)*64 + kw*32 + q*8);
    #pragma unroll
    for (int nt=0;nt<4;++nt)
      bv[nt] = *(const bf8v*)(Ttc + (nt*16+lr)*64 + kw*32 + q*8);
    #pragma unroll
    for (int mt=0;mt<4;++mt)
      #pragma unroll
      for (int nt=0;nt<4;++nt)
        acc[mt][nt] = __builtin_amdgcn_mfma_f32_16x16x32_bf16(af[mt], bv[nt], acc[mt][nt], 0,0,0);
  }
  #pragma unroll
  for (int kw = 0; kw < 2; ++kw){
    bf8v af[4], bv[4];
    #pragma unroll
    for (int mt=0;mt<4;++mt)
      af[mt] = *(const bf8v*)&s0buf[wv][mt*16+lr][kw*32 + q*8];
    #pragma unroll
    for (int nt=0;nt<4;++nt)
      bv[nt] = *(const bf8v*)(B2c + (nt*16+lr)*64 + kw*32 + q*8);
    #pragma unroll
    for (int mt=0;mt<4;++mt)
      #pragma unroll
      for (int nt=0;nt<4;++nt)
        acc[mt][nt] = __builtin_amdgcn_mfma_f32_16x16x32_bf16(af[mt], bv[nt], acc[mt][nt], 0,0,0);
  }
  __syncthreads();

  // ---- epilogue: gelu -> bf16, stage in LDS (reuse gbuf), coalesced store ----
  unsigned short (*ybuf)[72] = (unsigned short(*)[72])&gbuf[wv][0][0];
  #pragma unroll
  for (int mt=0;mt<4;++mt)
    #pragma unroll
    for (int nt=0;nt<4;++nt)
      #pragma unroll
      for (int r=0;r<4;++r)
        ybuf[mt*16 + q*4 + r][nt*16 + lr] = bfbits(fast_gelu(acc[mt][nt][r]));
  __syncthreads();
  u16x8* dst = (u16x8*)(gout + (size_t)seq*TT);
  for (int i = l; i < 512; i += 64){
    int row = i >> 3, cq = i & 7;
    dst[i] = *(const u16x8*)&ybuf[row][cq*8];
  }
}

// ---------------- transpose [B][C][T] bf16 -> [B][T][C] bf16 (64x64 tiles) ----------------
__global__ __launch_bounds__(256) void tr_kernel(const __bf16* __restrict__ gin,
                                                 __bf16* __restrict__ gout)
{
  __shared__ __align__(16) unsigned short ts[64][72];
  int bt = blockIdx.x;
  int bc = blockIdx.y;
  int b  = blockIdx.z;
  int tid = threadIdx.x;
  const __bf16* gp = gin + ((size_t)b*CC + bc*64)*TT + (size_t)bt*64;
  for (int i = tid; i < 512; i += 256){
    int c = i >> 3, tq = i & 7;
    u16x8 v = *(const u16x8*)(gp + (size_t)c*TT + tq*8);
    #pragma unroll
    for (int s = 0; s < 8; ++s) ts[tq*8+s][c] = v[s];
  }
  __syncthreads();
  __bf16* op = gout + ((size_t)b*TT + bt*64)*CC + bc*64;
  for (int i = tid; i < 512; i += 256){
    int t = i >> 3, cq = i & 7;
    u16x8 v = *(const u16x8*)&ts[t][cq*8];
    *(u16x8*)(op + (size_t)t*CC + cq*8) = v;
  }
}

// ---------------- fp32 -> bf16 weight convert ----------------
__global__ __launch_bounds__(256) void cvt_kernel(const float4* __restrict__ in,
                                                  bf4v* __restrict__ out, int n4)
{
  int i = blockIdx.x*256 + threadIdx.x;
  if (i < n4){
    float4 v = in[i];
    bf4v o; o[0]=(__bf16)v.x; o[1]=(__bf16)v.y; o[2]=(__bf16)v.z; o[3]=(__bf16)v.w;
    out[i] = o;
  }
}

// ---------------- bf16 MFMA GEMM, both operands row-major-K ----------------
template<int MODE>
__global__ __launch_bounds__(256, 2) void mm_kernel(
    const __bf16* __restrict__ Aw, const __bf16* __restrict__ Bt,
    const float* __restrict__ bias, const float* __restrict__ aux,
    void* __restrict__ outp, int K)
{
  __shared__ __align__(16) __bf16 As[128*32];
  __shared__ __align__(16) __bf16 Bs[128*32];
  __shared__ __align__(16) __bf16 As2[(MODE==0)?128*32:8];

  const int tid = threadIdx.x;
  const int l = tid & 63;
  const int lr = l & 15, kh = l >> 4;
  const int w = tid >> 6;
  const int wr = w >> 1, wc = w & 1;
  const int m0 = blockIdx.y * 128, n0 = blockIdx.x * 128;

  f4v acc[4][4];
  f4v acc2[(MODE==0)?4:1][(MODE==0)?4:1];
  #pragma unroll
  for (int a=0;a<4;++a)
    #pragma unroll
    for (int bq=0;bq<4;++bq)
      #pragma unroll
      for (int r=0;r<4;++r){
        acc[a][bq][r] = 0.f;
        if constexpr (MODE==0) acc2[a][bq][r] = 0.f;
      }

  const char* pA = (const char*)Aw;
  const char* pB = (const char*)Bt;

  for (int k0 = 0; k0 < K; k0 += 32){
    #pragma unroll
    for (int i = 0; i < 2; ++i){
      int cch = i*256 + tid;
      int row = cch >> 2;
      int kb  = (cch & 3) * 16;
      gload16(pA + ((size_t)(m0 + row)*K + k0)*2 + kb, (char*)As + cch*16);
      gload16(pB + ((size_t)(n0 + row)*K + k0)*2 + kb, (char*)Bs + cch*16);
      if constexpr (MODE==0)
        gload16(pA + ((size_t)(CC + m0 + row)*K + k0)*2 + kb, (char*)As2 + cch*16);
    }
    __syncthreads();
    bf8v af[4], bfv[4];
    #pragma unroll
    for (int mi=0;mi<4;++mi)
      af[mi] = *(const bf8v*)&As[(wr*64 + mi*16 + lr)*32 + kh*8];
    #pragma unroll
    for (int ni=0;ni<4;++ni)
      bfv[ni] = *(const bf8v*)&Bs[(wc*64 + ni*16 + lr)*32 + kh*8];
    if constexpr (MODE==0){
      bf8v af2[4];
      #pragma unroll
      for (int mi=0;mi<4;++mi)
        af2[mi] = *(const bf8v*)&As2[(wr*64 + mi*16 + lr)*32 + kh*8];
      #pragma unroll
      for (int mi=0;mi<4;++mi)
        #pragma unroll
        for (int ni=0;ni<4;++ni){
          acc [mi][ni] = __builtin_amdgcn_mfma_f32_16x16x32_bf16(af [mi], bfv[ni], acc [mi][ni], 0,0,0);
          acc2[mi][ni] = __builtin_amdgcn_mfma_f32_16x16x32_bf16(af2[mi], bfv[ni], acc2[mi][ni], 0,0,0);
        }
    } else {
      #pragma unroll
      for (int mi=0;mi<4;++mi)
        #pragma unroll
        for (int ni=0;ni<4;++ni)
          acc[mi][ni] = __builtin_amdgcn_mfma_f32_16x16x32_bf16(af[mi], bfv[ni], acc[mi][ni], 0,0,0);
    }
    __syncthreads();
  }

  if constexpr (MODE==0 || MODE==1){
    const int COUT = (MODE==0) ? CC : HH;
    __bf16* O = (__bf16*)outp;
    #pragma unroll
    for (int mi=0;mi<4;++mi){
      int m = m0 + wr*64 + mi*16 + kh*4;
      float4 bi = *(const float4*)&bias[m];
      float bia[4] = {bi.x, bi.y, bi.z, bi.w};
      float gta[4], paa[4];
      if constexpr (MODE==0){
        float4 bg = *(const float4*)&bias[CC + m];
        gta[0]=bg.x; gta[1]=bg.y; gta[2]=bg.z; gta[3]=bg.w;
      } else {
        float4 pa = *(const float4*)&aux[m];
        paa[0]=pa.x; paa[1]=pa.y; paa[2]=pa.z; paa[3]=pa.w;
      }
      #pragma unroll
      for (int ni=0;ni<4;++ni){
        int tok = n0 + wc*64 + ni*16 + lr;
        bf4v o;
        #pragma unroll
        for (int r=0;r<4;++r){
          float v = acc[mi][ni][r] + bia[r];
          if constexpr (MODE==0){
            float gate = acc2[mi][ni][r] + gta[r];
            v = v * fast_sigmoid(gate);
          } else {
            v = (v >= 0.f) ? v : paa[r]*v;
          }
          o[r] = (__bf16)v;
        }
        *(bf4v*)&O[(size_t)tok*COUT + m] = o;
      }
    }
  } else {
    float* O = (float*)outp;
    #pragma unroll
    for (int mi=0;mi<4;++mi){
      int mrow = m0 + wr*64 + mi*16 + kh*4;
      int bl = mrow >> 12, t = mrow & 4095;
      #pragma unroll
      for (int ni=0;ni<4;++ni){
        int ch = n0 + wc*64 + ni*16 + lr;
        size_t base = ((size_t)(bl*CC + ch))*TT + t;
        float4 xr = *(const float4*)&aux[base];
        float bb2 = bias[ch];
        float4 o;
        o.x = acc[mi][ni][0] + bb2 + xr.x;
        o.y = acc[mi][ni][1] + bb2 + xr.y;
        o.z = acc[mi][ni][2] + bb2 + xr.z;
        o.w = acc[mi][ni][3] + bb2 + xr.w;
        *(float4*)&O[base] = o;
      }
    }
  }
}

// ---------------- host launch ----------------
extern "C" void kernel_launch(void* const* d_in, const int* in_sizes, int n_in,
                              void* d_out, int out_size, void* d_ws, size_t ws_size,
                              hipStream_t stream)
{
  const float* x          = (const float*)d_in[0];
  const float* gamma      = (const float*)d_in[1];
  const float* beta       = (const float*)d_in[2];
  const float* log_dt     = (const float*)d_in[3];
  const float* C_re       = (const float*)d_in[4];
  const float* C_im       = (const float*)d_in[5];
  const float* log_A_real = (const float*)d_in[6];
  const float* A_imag     = (const float*)d_in[7];
  const float* Dp         = (const float*)d_in[8];
  const float* Wo         = (const float*)d_in[9];
  const float* bo         = (const float*)d_in[10];
  const float* W1         = (const float*)d_in[11];
  const float* b1         = (const float*)d_in[12];
  const float* prelu_a    = (const float*)d_in[13];
  const float* W2         = (const float*)d_in[14];
  const float* b2         = (const float*)d_in[15];
  float* out = (float*)d_out;

  char* base = (char*)d_ws;
  const size_t SEGB = (size_t)BB*CC*TT*2;        // 16.78 MB bf16 plane
  __bf16* u_bf  = (__bf16*)(base);               // [B][C][T]
  __bf16* g_cm  = (__bf16*)(base + SEGB);        // [B][C][T]
  __bf16* g_tm  = (__bf16*)(base + 2*SEGB);      // [B*T][C]
  __bf16* glu   = g_cm;                          // aliases (g_cm dead after tr)
  __bf16* h     = (__bf16*)(base + 3*SEGB);      // [8192][H] per 2-batch slab
  // S4D basis matrices alias h (h first written after s4dm is done)
  __bf16* Tt_all = (__bf16*)(base + 3*SEGB);
  __bf16* V_all  = Tt_all + (size_t)CC*4096;
  __bf16* B2_all = V_all  + (size_t)CC*4096;
  __bf16* Wo_bf = (__bf16*)(base + 3*SEGB + (size_t)2*TT*HH*2);
  __bf16* W1_bf = Wo_bf + (size_t)2*CC*CC;
  __bf16* W2_bf = W1_bf + (size_t)HH*CC;

  cvt_kernel<<<dim3((2*CC*CC/4 + 255)/256), 256, 0, stream>>>((const float4*)Wo, (bf4v*)Wo_bf, 2*CC*CC/4);
  cvt_kernel<<<dim3((HH*CC/4 + 255)/256), 256, 0, stream>>>((const float4*)W1, (bf4v*)W1_bf, HH*CC/4);
  cvt_kernel<<<dim3((CC*HH/4 + 255)/256), 256, 0, stream>>>((const float4*)W2, (bf4v*)W2_bf, CC*HH/4);

  build_mats<<<dim3(CC/4), 256, 0, stream>>>(log_dt, C_re, C_im, log_A_real,
                                             A_imag, Dp, Tt_all, V_all, B2_all);
  ln_kernel<<<dim3(BB*(TT/64)), 256, 0, stream>>>(x, gamma, beta, u_bf);
  s4dm_kernel<<<dim3((BB*CC)/2), 128, 0, stream>>>(u_bf, log_dt, log_A_real, A_imag,
                                                   Tt_all, V_all, B2_all, g_cm);
  tr_kernel<<<dim3(TT/64, CC/64, BB), 256, 0, stream>>>(g_cm, g_tm);
  mm_kernel<0><<<dim3((BB*TT)/128, CC/128), 256, 0, stream>>>(
      Wo_bf, g_tm, bo, nullptr, (void*)glu, CC);
  for (int bb = 0; bb < 2; ++bb){
    const __bf16* glu_s = glu + (size_t)bb*2*TT*CC;
    mm_kernel<1><<<dim3((2*TT)/128, HH/128), 256, 0, stream>>>(
        W1_bf, glu_s, b1, prelu_a, (void*)h, CC);
    mm_kernel<2><<<dim3(CC/128, (2*TT)/128), 256, 0, stream>>>(
        h, W2_bf, b2, x + (size_t)bb*2*CC*TT, (void*)(out + (size_t)bb*2*CC*TT), HH);
  }
}

// Round 5
// 243.110 us; speedup vs baseline: 5.4851x; 1.0360x over previous
//
#include <hip/hip_runtime.h>
#include <math.h>

#define BB 4
#define CC 512
#define TT 4096
#define NN2 32
#define HH 2048

typedef __bf16 bf8v __attribute__((ext_vector_type(8)));
typedef __bf16 bf4v __attribute__((ext_vector_type(4)));
typedef float  f4v  __attribute__((ext_vector_type(4)));
typedef unsigned short u16x8 __attribute__((ext_vector_type(8)));

__device__ __forceinline__ void gload16(const void* g, void* l){
  __builtin_amdgcn_global_load_lds(
      (const __attribute__((address_space(1))) unsigned int*)g,
      (__attribute__((address_space(3))) unsigned int*)l, 16, 0, 0);
}
__device__ __forceinline__ float fast_gelu(float v){
  float x2 = v*v;
  float x  = 0.7978845608f*v*fmaf(0.044715f, x2, 1.0f);
  float t  = __expf(2.0f*x);
  return v - v*__builtin_amdgcn_rcpf(1.0f + t);
}
__device__ __forceinline__ float fast_sigmoid(float g){
  return __builtin_amdgcn_rcpf(1.0f + __expf(-g));
}
__device__ __forceinline__ unsigned short bfbits(float v){
  __bf16 h = (__bf16)v;
  return __builtin_bit_cast(unsigned short, h);
}

// ---------------- ChannelwiseLayerNorm over C of [B, C, T] -> bf16 ----------------
__global__ __launch_bounds__(256) void ln_kernel(
    const float* __restrict__ x, const float* __restrict__ gamma,
    const float* __restrict__ beta, __bf16* __restrict__ u)
{
  int tile = blockIdx.x & (TT/64 - 1);
  int b    = blockIdx.x >> 6;
  int tl = threadIdx.x & 63;
  int cg = threadIdx.x >> 6;
  int t = tile*64 + tl;
  const float* xp = x + (size_t)b*CC*TT + t;
  float s = 0.f, s2 = 0.f;
  #pragma unroll 4
  for (int c = cg*128; c < (cg+1)*128; ++c){
    float v = xp[(size_t)c*TT];
    s += v; s2 = fmaf(v, v, s2);
  }
  __shared__ float ls[4][64], ls2[4][64], mean_s[64], inv_s[64];
  ls[cg][tl] = s; ls2[cg][tl] = s2;
  __syncthreads();
  if (threadIdx.x < 64){
    float ss  = ls [0][tl]+ls [1][tl]+ls [2][tl]+ls [3][tl];
    float ss2 = ls2[0][tl]+ls2[1][tl]+ls2[2][tl]+ls2[3][tl];
    float mean = ss * (1.f/CC);
    float var  = ss2 * (1.f/CC) - mean*mean;
    mean_s[tl] = mean;
    inv_s[tl]  = rsqrtf(var + 1e-5f);
  }
  __syncthreads();
  float mean = mean_s[tl], inv = inv_s[tl];
  __bf16* up = u + (size_t)b*CC*TT + t;
  #pragma unroll 4
  for (int c = cg*128; c < (cg+1)*128; ++c){
    float v = xp[(size_t)c*TT];
    up[(size_t)c*TT] = (__bf16)fmaf(gamma[c]*inv, v - mean, beta[c]);
  }
}

// ---------------- build per-channel S4D basis matrices (bf16) ----------------
__global__ __launch_bounds__(256) void build_mats(
    const float* __restrict__ log_dt, const float* __restrict__ C_re,
    const float* __restrict__ C_im, const float* __restrict__ log_A_real,
    const float* __restrict__ A_imag, const float* __restrict__ Dp,
    __bf16* __restrict__ Tt, __bf16* __restrict__ V, __bf16* __restrict__ B2)
{
  __shared__ float cpart[4][64][33];
  __shared__ float kk[4][65];
  const int wv = threadIdx.x >> 6, lane = threadIdx.x & 63;
  const int c = blockIdx.x*4 + wv;
  const int m = lane & 31;
  float dt = expf(log_dt[c]);
  float Ar = -expf(log_A_real[c*NN2+m]);
  float Ai = A_imag[c*NN2+m];
  float er = expf(Ar*dt);
  float sw_, cw_; sincosf(Ai*dt, &sw_, &cw_);
  float wre = er*cw_, wim = er*sw_;
  float nr = wre-1.f, ni = wim;
  float inv = 1.f/(Ar*Ar + Ai*Ai);
  float qr = (nr*Ar + ni*Ai)*inv;
  float qi = (ni*Ar - nr*Ai)*inv;
  float Cr = C_re[c*NN2+m], Ci = C_im[c*NN2+m];
  float okr =  2.f*(Cr*qr - Ci*qi);
  float oki = -2.f*(Cr*qi + Ci*qr);
  __bf16* Ttc = Tt + (size_t)c*4096;
  __bf16* Vc  = V  + (size_t)c*4096;
  __bf16* B2c = B2 + (size_t)c*4096;
  if (lane < 32){
    float pre = 1.f, pim = 0.f;
    for (int l = 0; l <= 64; ++l){
      if (l <= 63){
        Vc[(2*m)*64   + (63-l)] = (__bf16)pre;
        Vc[(2*m+1)*64 + (63-l)] = (__bf16)pim;
      }
      float cR = fmaf(okr, pre,  oki*pim);
      float cQ = fmaf(oki, pre, -okr*pim);
      if (l <= 63) cpart[wv][l][m] = cR;
      if (l >= 1){
        B2c[(l-1)*64 + 2*m]   = (__bf16)cR;
        B2c[(l-1)*64 + 2*m+1] = (__bf16)cQ;
      }
      float npre = wre*pre - wim*pim;
      float npim = wre*pim + wim*pre;
      pre = npre; pim = npim;
    }
  }
  __syncthreads();
  float s = 0.f;
  #pragma unroll
  for (int mm = 0; mm < 32; ++mm) s += cpart[wv][lane][mm];
  if (lane == 0) s += Dp[c];
  kk[wv][lane] = s;
  __syncthreads();
  const int n = lane;
  #pragma unroll
  for (int kb = 0; kb < 8; ++kb){
    u16x8 v;
    #pragma unroll
    for (int e = 0; e < 8; ++e){
      int k = kb*8 + e;
      v[e] = bfbits((n >= k) ? kk[wv][n-k] : 0.f);
    }
    *(u16x8*)&Ttc[n*64 + kb*8] = v;
  }
}

// ---------------- fused S4D via MFMA: G=U@V -> scan -> Y=U@Tt+S0@B2 -> gelu ----------------
__global__ __launch_bounds__(128) void s4dm_kernel(
    const __bf16* __restrict__ u, const float* __restrict__ log_dt,
    const float* __restrict__ log_A_real, const float* __restrict__ A_imag,
    const __bf16* __restrict__ Tt, const __bf16* __restrict__ V,
    const __bf16* __restrict__ B2, __bf16* __restrict__ gout)
{
  __shared__ __align__(16) float gbuf[2][64][66];
  __shared__ __align__(16) unsigned short s0buf[2][64][72];
  const int wv = threadIdx.x >> 6, l = threadIdx.x & 63;
  const int lr = l & 15, q = l >> 4;
  const int seq = blockIdx.x*2 + wv;
  const int c = seq & (CC-1);
  const __bf16* Up  = u  + (size_t)seq*TT;
  const __bf16* Ttc = Tt + (size_t)c*4096;
  const __bf16* Vc  = V  + (size_t)c*4096;
  const __bf16* B2c = B2 + (size_t)c*4096;

  f4v acc[4][4];
  #pragma unroll
  for (int a=0;a<4;++a)
    #pragma unroll
    for (int b=0;b<4;++b)
      #pragma unroll
      for (int r=0;r<4;++r) acc[a][b][r] = 0.f;

  // ---- G = U @ V ----
  #pragma unroll
  for (int kw = 0; kw < 2; ++kw){
    bf8v af[4], bv[4];
    #pragma unroll
    for (int mt=0;mt<4;++mt)
      af[mt] = *(const bf8v*)(Up + (mt*16+lr)*64 + kw*32 + q*8);
    #pragma unroll
    for (int nt=0;nt<4;++nt)
      bv[nt] = *(const bf8v*)(Vc + (nt*16+lr)*64 + kw*32 + q*8);
    #pragma unroll
    for (int mt=0;mt<4;++mt)
      #pragma unroll
      for (int nt=0;nt<4;++nt)
        acc[mt][nt] = __builtin_amdgcn_mfma_f32_16x16x32_bf16(af[mt], bv[nt], acc[mt][nt], 0,0,0);
  }
  #pragma unroll
  for (int mt=0;mt<4;++mt)
    #pragma unroll
    for (int nt=0;nt<4;++nt)
      #pragma unroll
      for (int r=0;r<4;++r)
        gbuf[wv][mt*16 + q*4 + r][nt*16 + lr] = acc[mt][nt][r];
  __syncthreads();

  // ---- carry scan over 64 chunks (lanes 0..31, one complex mode each) ----
  if (l < 32){
    const int m = l;
    float dt = expf(log_dt[c]);
    float Ar = -expf(log_A_real[c*NN2+m]);
    float Ai = A_imag[c*NN2+m];
    float er = expf(Ar*dt);
    float sw_, cw_; sincosf(Ai*dt, &sw_, &cw_);
    float wr_ = er*cw_, wi_ = er*sw_;
    #pragma unroll
    for (int sq2=0;sq2<6;++sq2){
      float a=wr_, b=wi_;
      wr_ = a*a - b*b; wi_ = 2.f*a*b;
    }
    float S0r=0.f, S0i=0.f;
    for (int j=0;j<64;++j){
      float gr = gbuf[wv][j][2*m], gi = gbuf[wv][j][2*m+1];
      s0buf[wv][j][2*m]   = bfbits(S0r);
      s0buf[wv][j][2*m+1] = bfbits(S0i);
      float nRe = fmaf(wr_, S0r, fmaf(-wi_, S0i, gr));
      float nIm = fmaf(wr_, S0i, fmaf( wi_, S0r, gi));
      S0r = nRe; S0i = nIm;
    }
  }
  __syncthreads();

  // ---- Y = U @ Tt + S0 @ B2 ----
  #pragma unroll
  for (int a=0;a<4;++a)
    #pragma unroll
    for (int b=0;b<4;++b)
      #pragma unroll
      for (int r=0;r<4;++r) acc[a][b][r] = 0.f;
  #pragma unroll
  for (int kw = 0; kw < 2; ++kw){
    bf8v af[4], bv[4];
    #pragma unroll
    for (int mt=0;mt<4;++mt)
      af[mt] = *(const bf8v*)(Up + (mt*16+lr)*64 + kw*32 + q*8);
    #pragma unroll
    for (int nt=0;nt<4;++nt)
      bv[nt] = *(const bf8v*)(Ttc + (nt*16+lr)*64 + kw*32 + q*8);
    #pragma unroll
    for (int mt=0;mt<4;++mt)
      #pragma unroll
      for (int nt=0;nt<4;++nt)
        acc[mt][nt] = __builtin_amdgcn_mfma_f32_16x16x32_bf16(af[mt], bv[nt], acc[mt][nt], 0,0,0);
  }
  #pragma unroll
  for (int kw = 0; kw < 2; ++kw){
    bf8v af[4], bv[4];
    #pragma unroll
    for (int mt=0;mt<4;++mt)
      af[mt] = *(const bf8v*)&s0buf[wv][mt*16+lr][kw*32 + q*8];
    #pragma unroll
    for (int nt=0;nt<4;++nt)
      bv[nt] = *(const bf8v*)(B2c + (nt*16+lr)*64 + kw*32 + q*8);
    #pragma unroll
    for (int mt=0;mt<4;++mt)
      #pragma unroll
      for (int nt=0;nt<4;++nt)
        acc[mt][nt] = __builtin_amdgcn_mfma_f32_16x16x32_bf16(af[mt], bv[nt], acc[mt][nt], 0,0,0);
  }
  __syncthreads();

  // ---- epilogue: gelu -> bf16, stage in LDS, coalesced store ----
  unsigned short (*ybuf)[72] = (unsigned short(*)[72])&gbuf[wv][0][0];
  #pragma unroll
  for (int mt=0;mt<4;++mt)
    #pragma unroll
    for (int nt=0;nt<4;++nt)
      #pragma unroll
      for (int r=0;r<4;++r)
        ybuf[mt*16 + q*4 + r][nt*16 + lr] = bfbits(fast_gelu(acc[mt][nt][r]));
  __syncthreads();
  u16x8* dst = (u16x8*)(gout + (size_t)seq*TT);
  for (int i = l; i < 512; i += 64){
    int row = i >> 3, cq = i & 7;
    dst[i] = *(const u16x8*)&ybuf[row][cq*8];
  }
}

// ---------------- transpose [B][C][T] bf16 -> [B][T][C] bf16 ----------------
__global__ __launch_bounds__(256) void tr_kernel(const __bf16* __restrict__ gin,
                                                 __bf16* __restrict__ gout)
{
  __shared__ __align__(16) unsigned short ts[64][72];
  int bt = blockIdx.x;
  int bc = blockIdx.y;
  int b  = blockIdx.z;
  int tid = threadIdx.x;
  const __bf16* gp = gin + ((size_t)b*CC + bc*64)*TT + (size_t)bt*64;
  for (int i = tid; i < 512; i += 256){
    int c = i >> 3, tq = i & 7;
    u16x8 v = *(const u16x8*)(gp + (size_t)c*TT + tq*8);
    #pragma unroll
    for (int s = 0; s < 8; ++s) ts[tq*8+s][c] = v[s];
  }
  __syncthreads();
  __bf16* op = gout + ((size_t)b*TT + bt*64)*CC + bc*64;
  for (int i = tid; i < 512; i += 256){
    int t = i >> 3, cq = i & 7;
    u16x8 v = *(const u16x8*)&ts[t][cq*8];
    *(u16x8*)(op + (size_t)t*CC + cq*8) = v;
  }
}

// ---------------- fp32 -> bf16 weight convert ----------------
__global__ __launch_bounds__(256) void cvt_kernel(const float4* __restrict__ in,
                                                  bf4v* __restrict__ out, int n4)
{
  int i = blockIdx.x*256 + threadIdx.x;
  if (i < n4){
    float4 v = in[i];
    bf4v o; o[0]=(__bf16)v.x; o[1]=(__bf16)v.y; o[2]=(__bf16)v.z; o[3]=(__bf16)v.w;
    out[i] = o;
  }
}

// ---------------- bf16 MFMA GEMM, both operands row-major-K ----------------
// D[m][n] = sum_k Aw[m][k] * Bt[n][k], 128xBN tile, BK=32.
// MODE 0: GLU   — grid (128,4):  m=Wo-ch,  n=tok.  BN=128.
// MODE 1: PReLU — grid (64,16):  m=W1-row, n=tok.  BN=128.
// MODE 2: resid — grid (8,64):   m=tok,    n=W2-ch. BN=64 (512 blocks, 2/CU).
// All use bijective XCD-chunk swizzle; the SMALLER grid dim iterates fastest
// within a chunk so one chunk's operand working set fits the 4MB per-XCD L2.
template<int MODE>
__global__ __launch_bounds__(256, 2) void mm_kernel(
    const __bf16* __restrict__ Aw, const __bf16* __restrict__ Bt,
    const float* __restrict__ bias, const float* __restrict__ aux,
    void* __restrict__ outp, int K)
{
  constexpr int BN = (MODE==2) ? 64 : 128;
  constexpr int NT = BN/32;            // n-tiles per wave
  __shared__ __align__(16) __bf16 As[128*32];
  __shared__ __align__(16) __bf16 Bs[BN*32];
  __shared__ __align__(16) __bf16 As2[(MODE==0)?128*32:8];

  constexpr int LOG_GX = (MODE==0)?7:(MODE==1)?6:3;
  constexpr int NWG    = (MODE==1)?1024:512;
  constexpr int QXCD   = NWG/8;
  int bid = ((int)blockIdx.y << LOG_GX) | (int)blockIdx.x;
  int swz = (bid & 7)*QXCD + (bid >> 3);
  int tx, ty;
  if constexpr (MODE==0){ ty = swz & 3;  tx = swz >> 2; }       // y (4) fastest
  else if constexpr (MODE==1){ ty = swz & 15; tx = swz >> 4; }  // y (16) fastest
  else { tx = swz & 7;  ty = swz >> 3; }                        // x (8) fastest
  const int m0 = ty * 128;
  const int n0 = tx * BN;

  const int tid = threadIdx.x;
  const int l = tid & 63;
  const int lr = l & 15, kh = l >> 4;
  const int w = tid >> 6;
  const int wr = w >> 1, wc = w & 1;

  f4v acc[4][NT];
  f4v acc2[(MODE==0)?4:1][(MODE==0)?4:1];
  #pragma unroll
  for (int a=0;a<4;++a)
    #pragma unroll
    for (int bq=0;bq<NT;++bq)
      #pragma unroll
      for (int r=0;r<4;++r) acc[a][bq][r] = 0.f;
  if constexpr (MODE==0){
    #pragma unroll
    for (int a=0;a<4;++a)
      #pragma unroll
      for (int bq=0;bq<4;++bq)
        #pragma unroll
        for (int r=0;r<4;++r) acc2[a][bq][r] = 0.f;
  }

  const char* pA = (const char*)Aw;
  const char* pB = (const char*)Bt;

  for (int k0 = 0; k0 < K; k0 += 32){
    #pragma unroll
    for (int i = 0; i < 2; ++i){
      int cch = i*256 + tid;
      int row = cch >> 2;
      int kb  = (cch & 3) * 16;
      gload16(pA + ((size_t)(m0 + row)*K + k0)*2 + kb, (char*)As + cch*16);
      if constexpr (MODE==0)
        gload16(pA + ((size_t)(CC + m0 + row)*K + k0)*2 + kb, (char*)As2 + cch*16);
    }
    #pragma unroll
    for (int i = 0; i < BN/64; ++i){
      int cch = i*256 + tid;
      int row = cch >> 2;
      int kb  = (cch & 3) * 16;
      gload16(pB + ((size_t)(n0 + row)*K + k0)*2 + kb, (char*)Bs + cch*16);
    }
    __syncthreads();
    bf8v af[4], bfv[NT];
    #pragma unroll
    for (int mi=0;mi<4;++mi)
      af[mi] = *(const bf8v*)&As[(wr*64 + mi*16 + lr)*32 + kh*8];
    #pragma unroll
    for (int ni=0;ni<NT;++ni)
      bfv[ni] = *(const bf8v*)&Bs[(wc*(BN/2) + ni*16 + lr)*32 + kh*8];
    if constexpr (MODE==0){
      bf8v af2[4];
      #pragma unroll
      for (int mi=0;mi<4;++mi)
        af2[mi] = *(const bf8v*)&As2[(wr*64 + mi*16 + lr)*32 + kh*8];
      #pragma unroll
      for (int mi=0;mi<4;++mi)
        #pragma unroll
        for (int ni=0;ni<4;++ni){
          acc [mi][ni] = __builtin_amdgcn_mfma_f32_16x16x32_bf16(af [mi], bfv[ni], acc [mi][ni], 0,0,0);
          acc2[mi][ni] = __builtin_amdgcn_mfma_f32_16x16x32_bf16(af2[mi], bfv[ni], acc2[mi][ni], 0,0,0);
        }
    } else {
      #pragma unroll
      for (int mi=0;mi<4;++mi)
        #pragma unroll
        for (int ni=0;ni<NT;++ni)
          acc[mi][ni] = __builtin_amdgcn_mfma_f32_16x16x32_bf16(af[mi], bfv[ni], acc[mi][ni], 0,0,0);
    }
    __syncthreads();
  }

  if constexpr (MODE==0 || MODE==1){
    const int COUT = (MODE==0) ? CC : HH;
    __bf16* O = (__bf16*)outp;
    #pragma unroll
    for (int mi=0;mi<4;++mi){
      int m = m0 + wr*64 + mi*16 + kh*4;
      float4 bi = *(const float4*)&bias[m];
      float bia[4] = {bi.x, bi.y, bi.z, bi.w};
      float gta[4], paa[4];
      if constexpr (MODE==0){
        float4 bg = *(const float4*)&bias[CC + m];
        gta[0]=bg.x; gta[1]=bg.y; gta[2]=bg.z; gta[3]=bg.w;
      } else {
        float4 pa = *(const float4*)&aux[m];
        paa[0]=pa.x; paa[1]=pa.y; paa[2]=pa.z; paa[3]=pa.w;
      }
      #pragma unroll
      for (int ni=0;ni<NT;++ni){
        int tok = n0 + wc*(BN/2) + ni*16 + lr;
        bf4v o;
        #pragma unroll
        for (int r=0;r<4;++r){
          float v = acc[mi][ni][r] + bia[r];
          if constexpr (MODE==0){
            float gate = acc2[mi][ni][r] + gta[r];
            v = v * fast_sigmoid(gate);
          } else {
            v = (v >= 0.f) ? v : paa[r]*v;
          }
          o[r] = (__bf16)v;
        }
        *(bf4v*)&O[(size_t)tok*COUT + m] = o;
      }
    }
  } else {
    float* O = (float*)outp;
    #pragma unroll
    for (int mi=0;mi<4;++mi){
      int mrow = m0 + wr*64 + mi*16 + kh*4;   // token within 2-batch slab
      int bl = mrow >> 12, t = mrow & 4095;
      #pragma unroll
      for (int ni=0;ni<NT;++ni){
        int ch = n0 + wc*(BN/2) + ni*16 + lr;
        size_t base = ((size_t)(bl*CC + ch))*TT + t;
        float4 xr = *(const float4*)&aux[base];
        float bb2 = bias[ch];
        float4 o;
        o.x = acc[mi][ni][0] + bb2 + xr.x;
        o.y = acc[mi][ni][1] + bb2 + xr.y;
        o.z = acc[mi][ni][2] + bb2 + xr.z;
        o.w = acc[mi][ni][3] + bb2 + xr.w;
        *(float4*)&O[base] = o;
      }
    }
  }
}

// ---------------- host launch ----------------
extern "C" void kernel_launch(void* const* d_in, const int* in_sizes, int n_in,
                              void* d_out, int out_size, void* d_ws, size_t ws_size,
                              hipStream_t stream)
{
  const float* x          = (const float*)d_in[0];
  const float* gamma      = (const float*)d_in[1];
  const float* beta       = (const float*)d_in[2];
  const float* log_dt     = (const float*)d_in[3];
  const float* C_re       = (const float*)d_in[4];
  const float* C_im       = (const float*)d_in[5];
  const float* log_A_real = (const float*)d_in[6];
  const float* A_imag     = (const float*)d_in[7];
  const float* Dp         = (const float*)d_in[8];
  const float* Wo         = (const float*)d_in[9];
  const float* bo         = (const float*)d_in[10];
  const float* W1         = (const float*)d_in[11];
  const float* b1         = (const float*)d_in[12];
  const float* prelu_a    = (const float*)d_in[13];
  const float* W2         = (const float*)d_in[14];
  const float* b2         = (const float*)d_in[15];
  float* out = (float*)d_out;

  char* base = (char*)d_ws;
  const size_t SEGB = (size_t)BB*CC*TT*2;        // 16.78 MB bf16 plane
  __bf16* u_bf  = (__bf16*)(base);               // [B][C][T]
  __bf16* g_cm  = (__bf16*)(base + SEGB);        // [B][C][T]
  __bf16* g_tm  = (__bf16*)(base + 2*SEGB);      // [B*T][C]
  __bf16* glu   = g_cm;                          // aliases (g_cm dead after tr)
  __bf16* h     = (__bf16*)(base + 3*SEGB);      // [8192][H] per 2-batch slab
  __bf16* Tt_all = (__bf16*)(base + 3*SEGB);     // basis alias h (dead before h)
  __bf16* V_all  = Tt_all + (size_t)CC*4096;
  __bf16* B2_all = V_all  + (size_t)CC*4096;
  __bf16* Wo_bf = (__bf16*)(base + 3*SEGB + (size_t)2*TT*HH*2);
  __bf16* W1_bf = Wo_bf + (size_t)2*CC*CC;
  __bf16* W2_bf = W1_bf + (size_t)HH*CC;

  cvt_kernel<<<dim3((2*CC*CC/4 + 255)/256), 256, 0, stream>>>((const float4*)Wo, (bf4v*)Wo_bf, 2*CC*CC/4);
  cvt_kernel<<<dim3((HH*CC/4 + 255)/256), 256, 0, stream>>>((const float4*)W1, (bf4v*)W1_bf, HH*CC/4);
  cvt_kernel<<<dim3((CC*HH/4 + 255)/256), 256, 0, stream>>>((const float4*)W2, (bf4v*)W2_bf, CC*HH/4);

  build_mats<<<dim3(CC/4), 256, 0, stream>>>(log_dt, C_re, C_im, log_A_real,
                                             A_imag, Dp, Tt_all, V_all, B2_all);
  ln_kernel<<<dim3(BB*(TT/64)), 256, 0, stream>>>(x, gamma, beta, u_bf);
  s4dm_kernel<<<dim3((BB*CC)/2), 128, 0, stream>>>(u_bf, log_dt, log_A_real, A_imag,
                                                   Tt_all, V_all, B2_all, g_cm);
  tr_kernel<<<dim3(TT/64, CC/64, BB), 256, 0, stream>>>(g_cm, g_tm);
  mm_kernel<0><<<dim3((BB*TT)/128, CC/128), 256, 0, stream>>>(
      Wo_bf, g_tm, bo, nullptr, (void*)glu, CC);
  for (int bb = 0; bb < 2; ++bb){
    const __bf16* glu_s = glu + (size_t)bb*2*TT*CC;
    mm_kernel<1><<<dim3((2*TT)/128, HH/128), 256, 0, stream>>>(
        W1_bf, glu_s, b1, prelu_a, (void*)h, CC);
    mm_kernel<2><<<dim3(CC/64, (2*TT)/128), 256, 0, stream>>>(
        h, W2_bf, b2, x + (size_t)bb*2*CC*TT, (void*)(out + (size_t)bb*2*CC*TT), HH);
  }
}

// Round 6
// 220.055 us; speedup vs baseline: 6.0598x; 1.1048x over previous
//
#include <hip/hip_runtime.h>
#include <math.h>

#define BB 4
#define CC 512
#define TT 4096
#define NN2 32
#define HH 2048

typedef __bf16 bf8v __attribute__((ext_vector_type(8)));
typedef __bf16 bf4v __attribute__((ext_vector_type(4)));
typedef float  f4v  __attribute__((ext_vector_type(4)));
typedef unsigned short u16x8 __attribute__((ext_vector_type(8)));

__device__ __forceinline__ void gload16(const void* g, void* l){
  __builtin_amdgcn_global_load_lds(
      (const __attribute__((address_space(1))) unsigned int*)g,
      (__attribute__((address_space(3))) unsigned int*)l, 16, 0, 0);
}
__device__ __forceinline__ float fast_gelu(float v){
  float x2 = v*v;
  float x  = 0.7978845608f*v*fmaf(0.044715f, x2, 1.0f);
  float t  = __expf(2.0f*x);
  return v - v*__builtin_amdgcn_rcpf(1.0f + t);
}
__device__ __forceinline__ float fast_sigmoid(float g){
  return __builtin_amdgcn_rcpf(1.0f + __expf(-g));
}
__device__ __forceinline__ unsigned short bfbits(float v){
  __bf16 h = (__bf16)v;
  return __builtin_bit_cast(unsigned short, h);
}

// ---------------- ChannelwiseLayerNorm over C of [B, C, T] -> bf16 ----------------
__global__ __launch_bounds__(256) void ln_kernel(
    const float* __restrict__ x, const float* __restrict__ gamma,
    const float* __restrict__ beta, __bf16* __restrict__ u)
{
  int tile = blockIdx.x & (TT/64 - 1);
  int b    = blockIdx.x >> 6;
  int tl = threadIdx.x & 63;
  int cg = threadIdx.x >> 6;
  int t = tile*64 + tl;
  const float* xp = x + (size_t)b*CC*TT + t;
  float s = 0.f, s2 = 0.f;
  #pragma unroll 4
  for (int c = cg*128; c < (cg+1)*128; ++c){
    float v = xp[(size_t)c*TT];
    s += v; s2 = fmaf(v, v, s2);
  }
  __shared__ float ls[4][64], ls2[4][64], mean_s[64], inv_s[64];
  ls[cg][tl] = s; ls2[cg][tl] = s2;
  __syncthreads();
  if (threadIdx.x < 64){
    float ss  = ls [0][tl]+ls [1][tl]+ls [2][tl]+ls [3][tl];
    float ss2 = ls2[0][tl]+ls2[1][tl]+ls2[2][tl]+ls2[3][tl];
    float mean = ss * (1.f/CC);
    float var  = ss2 * (1.f/CC) - mean*mean;
    mean_s[tl] = mean;
    inv_s[tl]  = rsqrtf(var + 1e-5f);
  }
  __syncthreads();
  float mean = mean_s[tl], inv = inv_s[tl];
  __bf16* up = u + (size_t)b*CC*TT + t;
  #pragma unroll 4
  for (int c = cg*128; c < (cg+1)*128; ++c){
    float v = xp[(size_t)c*TT];
    up[(size_t)c*TT] = (__bf16)fmaf(gamma[c]*inv, v - mean, beta[c]);
  }
}

// ---------------- build per-channel S4D basis matrices (bf16) ----------------
__global__ __launch_bounds__(256) void build_mats(
    const float* __restrict__ log_dt, const float* __restrict__ C_re,
    const float* __restrict__ C_im, const float* __restrict__ log_A_real,
    const float* __restrict__ A_imag, const float* __restrict__ Dp,
    __bf16* __restrict__ Tt, __bf16* __restrict__ V, __bf16* __restrict__ B2)
{
  __shared__ float cpart[4][64][33];
  __shared__ float kk[4][65];
  const int wv = threadIdx.x >> 6, lane = threadIdx.x & 63;
  const int c = blockIdx.x*4 + wv;
  const int m = lane & 31;
  float dt = expf(log_dt[c]);
  float Ar = -expf(log_A_real[c*NN2+m]);
  float Ai = A_imag[c*NN2+m];
  float er = expf(Ar*dt);
  float sw_, cw_; sincosf(Ai*dt, &sw_, &cw_);
  float wre = er*cw_, wim = er*sw_;
  float nr = wre-1.f, ni = wim;
  float inv = 1.f/(Ar*Ar + Ai*Ai);
  float qr = (nr*Ar + ni*Ai)*inv;
  float qi = (ni*Ar - nr*Ai)*inv;
  float Cr = C_re[c*NN2+m], Ci = C_im[c*NN2+m];
  float okr =  2.f*(Cr*qr - Ci*qi);
  float oki = -2.f*(Cr*qi + Ci*qr);
  __bf16* Ttc = Tt + (size_t)c*4096;
  __bf16* Vc  = V  + (size_t)c*4096;
  __bf16* B2c = B2 + (size_t)c*4096;
  if (lane < 32){
    float pre = 1.f, pim = 0.f;
    for (int l = 0; l <= 64; ++l){
      if (l <= 63){
        Vc[(2*m)*64   + (63-l)] = (__bf16)pre;
        Vc[(2*m+1)*64 + (63-l)] = (__bf16)pim;
      }
      float cR = fmaf(okr, pre,  oki*pim);
      float cQ = fmaf(oki, pre, -okr*pim);
      if (l <= 63) cpart[wv][l][m] = cR;
      if (l >= 1){
        B2c[(l-1)*64 + 2*m]   = (__bf16)cR;
        B2c[(l-1)*64 + 2*m+1] = (__bf16)cQ;
      }
      float npre = wre*pre - wim*pim;
      float npim = wre*pim + wim*pre;
      pre = npre; pim = npim;
    }
  }
  __syncthreads();
  float s = 0.f;
  #pragma unroll
  for (int mm = 0; mm < 32; ++mm) s += cpart[wv][lane][mm];
  if (lane == 0) s += Dp[c];
  kk[wv][lane] = s;
  __syncthreads();
  const int n = lane;
  #pragma unroll
  for (int kb = 0; kb < 8; ++kb){
    u16x8 v;
    #pragma unroll
    for (int e = 0; e < 8; ++e){
      int k = kb*8 + e;
      v[e] = bfbits((n >= k) ? kk[wv][n-k] : 0.f);
    }
    *(u16x8*)&Ttc[n*64 + kb*8] = v;
  }
}

// ---------------- fused S4D via MFMA: G=U@V -> scan -> Y=U@Tt+S0@B2 -> gelu ----------------
__global__ __launch_bounds__(128) void s4dm_kernel(
    const __bf16* __restrict__ u, const float* __restrict__ log_dt,
    const float* __restrict__ log_A_real, const float* __restrict__ A_imag,
    const __bf16* __restrict__ Tt, const __bf16* __restrict__ V,
    const __bf16* __restrict__ B2, __bf16* __restrict__ gout)
{
  __shared__ __align__(16) float gbuf[2][64][66];
  __shared__ __align__(16) unsigned short s0buf[2][64][72];
  const int wv = threadIdx.x >> 6, l = threadIdx.x & 63;
  const int lr = l & 15, q = l >> 4;
  const int seq = blockIdx.x*2 + wv;
  const int c = seq & (CC-1);
  const __bf16* Up  = u  + (size_t)seq*TT;
  const __bf16* Ttc = Tt + (size_t)c*4096;
  const __bf16* Vc  = V  + (size_t)c*4096;
  const __bf16* B2c = B2 + (size_t)c*4096;

  f4v acc[4][4];
  #pragma unroll
  for (int a=0;a<4;++a)
    #pragma unroll
    for (int b=0;b<4;++b)
      #pragma unroll
      for (int r=0;r<4;++r) acc[a][b][r] = 0.f;

  // ---- G = U @ V ----
  #pragma unroll
  for (int kw = 0; kw < 2; ++kw){
    bf8v af[4], bv[4];
    #pragma unroll
    for (int mt=0;mt<4;++mt)
      af[mt] = *(const bf8v*)(Up + (mt*16+lr)*64 + kw*32 + q*8);
    #pragma unroll
    for (int nt=0;nt<4;++nt)
      bv[nt] = *(const bf8v*)(Vc + (nt*16+lr)*64 + kw*32 + q*8);
    #pragma unroll
    for (int mt=0;mt<4;++mt)
      #pragma unroll
      for (int nt=0;nt<4;++nt)
        acc[mt][nt] = __builtin_amdgcn_mfma_f32_16x16x32_bf16(af[mt], bv[nt], acc[mt][nt], 0,0,0);
  }
  #pragma unroll
  for (int mt=0;mt<4;++mt)
    #pragma unroll
    for (int nt=0;nt<4;++nt)
      #pragma unroll
      for (int r=0;r<4;++r)
        gbuf[wv][mt*16 + q*4 + r][nt*16 + lr] = acc[mt][nt][r];
  __syncthreads();

  // ---- carry scan over 64 chunks ----
  if (l < 32){
    const int m = l;
    float dt = expf(log_dt[c]);
    float Ar = -expf(log_A_real[c*NN2+m]);
    float Ai = A_imag[c*NN2+m];
    float er = expf(Ar*dt);
    float sw_, cw_; sincosf(Ai*dt, &sw_, &cw_);
    float wr_ = er*cw_, wi_ = er*sw_;
    #pragma unroll
    for (int sq2=0;sq2<6;++sq2){
      float a=wr_, b=wi_;
      wr_ = a*a - b*b; wi_ = 2.f*a*b;
    }
    float S0r=0.f, S0i=0.f;
    for (int j=0;j<64;++j){
      float gr = gbuf[wv][j][2*m], gi = gbuf[wv][j][2*m+1];
      s0buf[wv][j][2*m]   = bfbits(S0r);
      s0buf[wv][j][2*m+1] = bfbits(S0i);
      float nRe = fmaf(wr_, S0r, fmaf(-wi_, S0i, gr));
      float nIm = fmaf(wr_, S0i, fmaf( wi_, S0r, gi));
      S0r = nRe; S0i = nIm;
    }
  }
  __syncthreads();

  // ---- Y = U @ Tt + S0 @ B2 ----
  #pragma unroll
  for (int a=0;a<4;++a)
    #pragma unroll
    for (int b=0;b<4;++b)
      #pragma unroll
      for (int r=0;r<4;++r) acc[a][b][r] = 0.f;
  #pragma unroll
  for (int kw = 0; kw < 2; ++kw){
    bf8v af[4], bv[4];
    #pragma unroll
    for (int mt=0;mt<4;++mt)
      af[mt] = *(const bf8v*)(Up + (mt*16+lr)*64 + kw*32 + q*8);
    #pragma unroll
    for (int nt=0;nt<4;++nt)
      bv[nt] = *(const bf8v*)(Ttc + (nt*16+lr)*64 + kw*32 + q*8);
    #pragma unroll
    for (int mt=0;mt<4;++mt)
      #pragma unroll
      for (int nt=0;nt<4;++nt)
        acc[mt][nt] = __builtin_amdgcn_mfma_f32_16x16x32_bf16(af[mt], bv[nt], acc[mt][nt], 0,0,0);
  }
  #pragma unroll
  for (int kw = 0; kw < 2; ++kw){
    bf8v af[4], bv[4];
    #pragma unroll
    for (int mt=0;mt<4;++mt)
      af[mt] = *(const bf8v*)&s0buf[wv][mt*16+lr][kw*32 + q*8];
    #pragma unroll
    for (int nt=0;nt<4;++nt)
      bv[nt] = *(const bf8v*)(B2c + (nt*16+lr)*64 + kw*32 + q*8);
    #pragma unroll
    for (int mt=0;mt<4;++mt)
      #pragma unroll
      for (int nt=0;nt<4;++nt)
        acc[mt][nt] = __builtin_amdgcn_mfma_f32_16x16x32_bf16(af[mt], bv[nt], acc[mt][nt], 0,0,0);
  }
  __syncthreads();

  // ---- epilogue ----
  unsigned short (*ybuf)[72] = (unsigned short(*)[72])&gbuf[wv][0][0];
  #pragma unroll
  for (int mt=0;mt<4;++mt)
    #pragma unroll
    for (int nt=0;nt<4;++nt)
      #pragma unroll
      for (int r=0;r<4;++r)
        ybuf[mt*16 + q*4 + r][nt*16 + lr] = bfbits(fast_gelu(acc[mt][nt][r]));
  __syncthreads();
  u16x8* dst = (u16x8*)(gout + (size_t)seq*TT);
  for (int i = l; i < 512; i += 64){
    int row = i >> 3, cq = i & 7;
    dst[i] = *(const u16x8*)&ybuf[row][cq*8];
  }
}

// ---------------- transpose [B][C][T] bf16 -> [B][T][C] bf16 ----------------
__global__ __launch_bounds__(256) void tr_kernel(const __bf16* __restrict__ gin,
                                                 __bf16* __restrict__ gout)
{
  __shared__ __align__(16) unsigned short ts[64][72];
  int bt = blockIdx.x;
  int bc = blockIdx.y;
  int b  = blockIdx.z;
  int tid = threadIdx.x;
  const __bf16* gp = gin + ((size_t)b*CC + bc*64)*TT + (size_t)bt*64;
  for (int i = tid; i < 512; i += 256){
    int c = i >> 3, tq = i & 7;
    u16x8 v = *(const u16x8*)(gp + (size_t)c*TT + tq*8);
    #pragma unroll
    for (int s = 0; s < 8; ++s) ts[tq*8+s][c] = v[s];
  }
  __syncthreads();
  __bf16* op = gout + ((size_t)b*TT + bt*64)*CC + bc*64;
  for (int i = tid; i < 512; i += 256){
    int t = i >> 3, cq = i & 7;
    u16x8 v = *(const u16x8*)&ts[t][cq*8];
    *(u16x8*)(op + (size_t)t*CC + cq*8) = v;
  }
}

// ---------------- fp32 -> bf16 weight convert ----------------
__global__ __launch_bounds__(256) void cvt_kernel(const float4* __restrict__ in,
                                                  bf4v* __restrict__ out, int n4)
{
  int i = blockIdx.x*256 + threadIdx.x;
  if (i < n4){
    float4 v = in[i];
    bf4v o; o[0]=(__bf16)v.x; o[1]=(__bf16)v.y; o[2]=(__bf16)v.z; o[3]=(__bf16)v.w;
    out[i] = o;
  }
}

// ---------------- bf16 MFMA GEMM: 128(M) x 256(N=tokens) tile, 8 waves, BK=32,
// double-buffered LDS with next-tile prefetch issued BEFORE compute (T3 minimum
// 2-phase), both-sides XOR swizzle (inverse-swizzled global source + swizzled
// ds_read), bijective XCD n-chunk decode.
// MODE 0: GLU   — A=Wo[1024][512] dual, B=g_tm[16384][512], out glu bf16 [tok][C]
// MODE 1: PReLU — A=W1[2048][512],      B=glu [16384][512], out h  bf16 [tok][H]
// MODE 2: resid — A=W2[512][2048],      B=h  [16384][2048], out fp32 [b][ch][t]
template<int MODE>
__global__ __launch_bounds__(512, 2) void mm_kernel(
    const __bf16* __restrict__ Aw, const __bf16* __restrict__ Bt,
    const float* __restrict__ bias, const float* __restrict__ aux,
    void* __restrict__ outp)
{
  constexpr int K  = (MODE==2) ? 2048 : 512;
  constexpr int NT = K/32;
  constexpr int LOGGM = (MODE==1) ? 4 : 2;
  constexpr int GM = 1 << LOGGM;

  __shared__ __align__(16) __bf16 As[2*128*32];
  __shared__ __align__(16) __bf16 Bs[2*256*32];
  __shared__ __align__(16) __bf16 As2[(MODE==0)?2*128*32:8];

  // XCD-bijective decode: xcd = bid&7 owns token-tiles [xcd*8, xcd*8+8)
  const int bid = blockIdx.x;
  const int X = bid & 7, L = bid >> 3;
  const int m0 = (L & (GM-1)) * 128;
  const int n0 = (X*8 + (L >> LOGGM)) * 256;

  const int tid = threadIdx.x;
  const int l = tid & 63;
  const int lr = l & 15, kh = l >> 4;
  const int w = tid >> 6;
  const int wm = w >> 2, wn = w & 3;      // 2 x 4 wave grid
  const int coff = (kh ^ ((lr ^ (lr >> 2)) & 3)) * 16;   // swizzled read chunk

  f4v acc[4][4];
  f4v acc2[(MODE==0)?4:1][(MODE==0)?4:1];
  #pragma unroll
  for (int a=0;a<4;++a)
    #pragma unroll
    for (int b=0;b<4;++b)
      #pragma unroll
      for (int r=0;r<4;++r) acc[a][b][r] = 0.f;
  if constexpr (MODE==0){
    #pragma unroll
    for (int a=0;a<4;++a)
      #pragma unroll
      for (int b=0;b<4;++b)
        #pragma unroll
        for (int r=0;r<4;++r) acc2[a][b][r] = 0.f;
  }

  const char* pA  = (const char*)Aw;
  const char* pA2 = (const char*)(Aw + (size_t)CC*K);   // gate half (MODE 0)
  const char* pB  = (const char*)Bt;

  auto stage = [&](int d, int kt){
    {  // A: 512 chunks of 16B
      int cch = tid;
      int row = cch >> 2;
      int kb = ((cch & 3) ^ ((row ^ (row >> 2)) & 3)) * 16;
      gload16(pA + ((size_t)(m0+row)*K + kt*32)*2 + kb, (char*)As + d*8192 + cch*16);
      if constexpr (MODE==0)
        gload16(pA2 + ((size_t)(m0+row)*K + kt*32)*2 + kb, (char*)As2 + d*8192 + cch*16);
    }
    #pragma unroll
    for (int i=0;i<2;++i){  // B: 1024 chunks
      int cch = i*512 + tid;
      int row = cch >> 2;
      int kb = ((cch & 3) ^ ((row ^ (row >> 2)) & 3)) * 16;
      gload16(pB + ((size_t)(n0+row)*K + kt*32)*2 + kb, (char*)Bs + d*16384 + cch*16);
    }
  };

  auto compute = [&](int d){
    bf8v af[4], bv4[4];
    #pragma unroll
    for (int mi=0;mi<4;++mi){
      int row = wm*64 + mi*16 + lr;
      af[mi] = *(const bf8v*)((const char*)As + d*8192 + row*64 + coff);
    }
    #pragma unroll
    for (int ni=0;ni<4;++ni){
      int row = wn*64 + ni*16 + lr;
      bv4[ni] = *(const bf8v*)((const char*)Bs + d*16384 + row*64 + coff);
    }
    if constexpr (MODE==0){
      bf8v af2[4];
      #pragma unroll
      for (int mi=0;mi<4;++mi){
        int row = wm*64 + mi*16 + lr;
        af2[mi] = *(const bf8v*)((const char*)As2 + d*8192 + row*64 + coff);
      }
      #pragma unroll
      for (int mi=0;mi<4;++mi)
        #pragma unroll
        for (int ni=0;ni<4;++ni){
          acc [mi][ni] = __builtin_amdgcn_mfma_f32_16x16x32_bf16(af [mi], bv4[ni], acc [mi][ni], 0,0,0);
          acc2[mi][ni] = __builtin_amdgcn_mfma_f32_16x16x32_bf16(af2[mi], bv4[ni], acc2[mi][ni], 0,0,0);
        }
    } else {
      #pragma unroll
      for (int mi=0;mi<4;++mi)
        #pragma unroll
        for (int ni=0;ni<4;++ni)
          acc[mi][ni] = __builtin_amdgcn_mfma_f32_16x16x32_bf16(af[mi], bv4[ni], acc[mi][ni], 0,0,0);
    }
  };

  stage(0, 0);
  __syncthreads();              // drains vmcnt(0): buf0 ready
  int cur = 0;
  #pragma unroll 1
  for (int kt = 1; kt < NT; ++kt){
    stage(cur ^ 1, kt);         // prefetch next tile: in flight during compute
    compute(cur);
    __syncthreads();            // drain -> buf[cur^1] ready; all waves done with buf[cur]
    cur ^= 1;
  }
  compute(cur);

  // ---- epilogues ----
  if constexpr (MODE==0 || MODE==1){
    const int COUT = (MODE==0) ? CC : HH;
    __bf16* O = (__bf16*)outp;
    #pragma unroll
    for (int mi=0;mi<4;++mi){
      int m = m0 + wm*64 + mi*16 + kh*4;
      float4 bi = *(const float4*)&bias[m];
      float bia[4] = {bi.x, bi.y, bi.z, bi.w};
      float gta[4], paa[4];
      if constexpr (MODE==0){
        float4 bg = *(const float4*)&bias[CC + m];
        gta[0]=bg.x; gta[1]=bg.y; gta[2]=bg.z; gta[3]=bg.w;
      } else {
        float4 pa = *(const float4*)&aux[m];
        paa[0]=pa.x; paa[1]=pa.y; paa[2]=pa.z; paa[3]=pa.w;
      }
      #pragma unroll
      for (int ni=0;ni<4;++ni){
        int tok = n0 + wn*64 + ni*16 + lr;
        bf4v o;
        #pragma unroll
        for (int r=0;r<4;++r){
          float v = acc[mi][ni][r] + bia[r];
          if constexpr (MODE==0){
            float gate = acc2[mi][ni][r] + gta[r];
            v = v * fast_sigmoid(gate);
          } else {
            v = (v >= 0.f) ? v : paa[r]*v;
          }
          o[r] = (__bf16)v;
        }
        *(bf4v*)&O[(size_t)tok*COUT + m] = o;
      }
    }
  } else {
    float* O = (float*)outp;
    #pragma unroll
    for (int mi=0;mi<4;++mi){
      int chb = m0 + wm*64 + mi*16 + kh*4;
      float4 bi = *(const float4*)&bias[chb];
      float bia[4] = {bi.x, bi.y, bi.z, bi.w};
      #pragma unroll
      for (int ni=0;ni<4;++ni){
        int tok = n0 + wn*64 + ni*16 + lr;
        int b = tok >> 12, t = tok & 4095;
        size_t rb = ((size_t)(b*CC + chb))*TT + t;
        #pragma unroll
        for (int r=0;r<4;++r)
          O[rb + (size_t)r*TT] = acc[mi][ni][r] + bia[r] + aux[rb + (size_t)r*TT];
      }
    }
  }
}

// ---------------- host launch ----------------
extern "C" void kernel_launch(void* const* d_in, const int* in_sizes, int n_in,
                              void* d_out, int out_size, void* d_ws, size_t ws_size,
                              hipStream_t stream)
{
  const float* x          = (const float*)d_in[0];
  const float* gamma      = (const float*)d_in[1];
  const float* beta       = (const float*)d_in[2];
  const float* log_dt     = (const float*)d_in[3];
  const float* C_re       = (const float*)d_in[4];
  const float* C_im       = (const float*)d_in[5];
  const float* log_A_real = (const float*)d_in[6];
  const float* A_imag     = (const float*)d_in[7];
  const float* Dp         = (const float*)d_in[8];
  const float* Wo         = (const float*)d_in[9];
  const float* bo         = (const float*)d_in[10];
  const float* W1         = (const float*)d_in[11];
  const float* b1         = (const float*)d_in[12];
  const float* prelu_a    = (const float*)d_in[13];
  const float* W2         = (const float*)d_in[14];
  const float* b2         = (const float*)d_in[15];
  float* out = (float*)d_out;

  char* base = (char*)d_ws;
  const size_t SEGB = (size_t)BB*CC*TT*2;        // 16.78 MB bf16 plane
  // Lifetimes: ln->u_bf; s4dm: u_bf->g_cm; tr: g_cm->g_tm; mm0: g_tm->glu;
  //            mm1: glu->h; mm2: h->out.
  __bf16* u_bf  = (__bf16*)(base);               // [B][C][T]
  __bf16* glu   = (__bf16*)(base);               // aliases u_bf (dead after s4dm)
  __bf16* g_cm  = (__bf16*)(base + SEGB);        // [B][C][T]
  __bf16* g_tm  = (__bf16*)(base + 2*SEGB);      // [B*T][C]
  __bf16* h     = (__bf16*)(base + SEGB);        // [16384][H], spans [S,5S) over dead g_cm/g_tm
  __bf16* Tt_all = (__bf16*)(base + 2*SEGB);     // basis alias g_tm (dead before tr writes)
  __bf16* V_all  = Tt_all + (size_t)CC*4096;
  __bf16* B2_all = V_all  + (size_t)CC*4096;
  __bf16* Wo_bf = (__bf16*)(base + 5*SEGB);      // weights: 5 MB
  __bf16* W1_bf = Wo_bf + (size_t)2*CC*CC;
  __bf16* W2_bf = W1_bf + (size_t)HH*CC;

  cvt_kernel<<<dim3((2*CC*CC/4 + 255)/256), 256, 0, stream>>>((const float4*)Wo, (bf4v*)Wo_bf, 2*CC*CC/4);
  cvt_kernel<<<dim3((HH*CC/4 + 255)/256), 256, 0, stream>>>((const float4*)W1, (bf4v*)W1_bf, HH*CC/4);
  cvt_kernel<<<dim3((CC*HH/4 + 255)/256), 256, 0, stream>>>((const float4*)W2, (bf4v*)W2_bf, CC*HH/4);

  build_mats<<<dim3(CC/4), 256, 0, stream>>>(log_dt, C_re, C_im, log_A_real,
                                             A_imag, Dp, Tt_all, V_all, B2_all);
  ln_kernel<<<dim3(BB*(TT/64)), 256, 0, stream>>>(x, gamma, beta, u_bf);
  s4dm_kernel<<<dim3((BB*CC)/2), 128, 0, stream>>>(u_bf, log_dt, log_A_real, A_imag,
                                                   Tt_all, V_all, B2_all, g_cm);
  tr_kernel<<<dim3(TT/64, CC/64, BB), 256, 0, stream>>>(g_cm, g_tm);

  // full-batch GEMMs (single dispatch each)
  mm_kernel<0><<<dim3(4*64),  512, 0, stream>>>(Wo_bf, g_tm, bo, nullptr, (void*)glu);
  mm_kernel<1><<<dim3(16*64), 512, 0, stream>>>(W1_bf, glu, b1, prelu_a, (void*)h);
  mm_kernel<2><<<dim3(4*64),  512, 0, stream>>>(W2_bf, h, b2, x, (void*)out);
}